// Round 2
// baseline (4248.005 us; speedup 1.0000x reference)
//
#include <hip/hip_runtime.h>

#define HH 512
#define WW 512
#define NB 8
#define HWSZ (HH * WW)
#define TS 16

// ---------------- conv1: 1 -> 32, 3x3 SAME, bias + prelu (single image) ----------------
__global__ __launch_bounds__(256) void k_conv1(const float* __restrict__ x,
                                               const float* __restrict__ w,
                                               const float* __restrict__ bias,
                                               const float* __restrict__ a_ptr,
                                               float* __restrict__ out) {
  __shared__ float tile[18][19];
  int h0 = blockIdx.y * TS, w0 = blockIdx.x * TS;
  int tx = threadIdx.x & 15, ty = threadIdx.x >> 4;
  for (int idx = threadIdx.x; idx < 18 * 18; idx += 256) {
    int r = idx / 18, c = idx % 18;
    int hh = h0 + r - 1, ww = w0 + c - 1;
    float v = 0.f;
    if (hh >= 0 && hh < HH && ww >= 0 && ww < WW) v = x[hh * WW + ww];
    tile[r][c] = v;
  }
  __syncthreads();
  float t[9];
#pragma unroll
  for (int kh = 0; kh < 3; kh++)
#pragma unroll
    for (int kw = 0; kw < 3; kw++) t[kh * 3 + kw] = tile[ty + kh][tx + kw];
  float a = a_ptr[0];
  int h = h0 + ty, wc = w0 + tx;
  float* op = out + h * WW + wc;
#pragma unroll
  for (int oc = 0; oc < 32; oc++) {
    float s = bias[oc];
#pragma unroll
    for (int k = 0; k < 9; k++) s = fmaf(w[oc * 9 + k], t[k], s);
    s = s >= 0.f ? s : a * s;
    op[oc * HWSZ] = s;
  }
}

// ---------------- generic IC->OC 3x3 SAME conv, bias + prelu (single image) ----------------
template <int IC, int OC>
__global__ __launch_bounds__(256) void k_conv(const float* __restrict__ in,
                                              const float* __restrict__ w,
                                              const float* __restrict__ bias,
                                              const float* __restrict__ a_ptr,
                                              float* __restrict__ out) {
  __shared__ float tile[18][19];
  int h0 = blockIdx.y * TS, w0 = blockIdx.x * TS;
  int tx = threadIdx.x & 15, ty = threadIdx.x >> 4;
  float acc[OC];
#pragma unroll
  for (int i = 0; i < OC; i++) acc[i] = 0.f;
  for (int ic = 0; ic < IC; ic++) {
    const float* xp = in + ic * HWSZ;
    __syncthreads();
    for (int idx = threadIdx.x; idx < 18 * 18; idx += 256) {
      int r = idx / 18, c = idx % 18;
      int hh = h0 + r - 1, ww = w0 + c - 1;
      float v = 0.f;
      if (hh >= 0 && hh < HH && ww >= 0 && ww < WW) v = xp[hh * WW + ww];
      tile[r][c] = v;
    }
    __syncthreads();
    float t[9];
#pragma unroll
    for (int kh = 0; kh < 3; kh++)
#pragma unroll
      for (int kw = 0; kw < 3; kw++) t[kh * 3 + kw] = tile[ty + kh][tx + kw];
    const float* wp = w + ic * 9;
#pragma unroll
    for (int oc = 0; oc < OC; oc++) {
      float s = acc[oc];
#pragma unroll
      for (int k = 0; k < 9; k++) s = fmaf(wp[oc * IC * 9 + k], t[k], s);
      acc[oc] = s;
    }
  }
  float a = a_ptr[0];
  int h = h0 + ty, wc = w0 + tx;
  float* op = out + h * WW + wc;
#pragma unroll
  for (int oc = 0; oc < OC; oc++) {
    float s = acc[oc] + bias[oc];
    s = s >= 0.f ? s : a * s;
    op[oc * HWSZ] = s;
  }
}

// ------- all 3 head convs fused: 32 -> 12 (3 heads x 4ch), + per-channel sums -------
__global__ __launch_bounds__(256) void k_headconv3(const float* __restrict__ in,
                                                   const float* __restrict__ w0p,
                                                   const float* __restrict__ w1p,
                                                   const float* __restrict__ w2p,
                                                   const float* __restrict__ b0p,
                                                   const float* __restrict__ b1p,
                                                   const float* __restrict__ b2p,
                                                   float* __restrict__ pre,
                                                   float* __restrict__ S) {
  __shared__ float tile[18][19];
  int h0 = blockIdx.y * TS, w0 = blockIdx.x * TS;
  int tx = threadIdx.x & 15, ty = threadIdx.x >> 4;
  const float* wp3[3] = {w0p, w1p, w2p};
  float acc[12];
#pragma unroll
  for (int i = 0; i < 12; i++) acc[i] = 0.f;
  for (int ic = 0; ic < 32; ic++) {
    const float* xp = in + ic * HWSZ;
    __syncthreads();
    for (int idx = threadIdx.x; idx < 18 * 18; idx += 256) {
      int r = idx / 18, c = idx % 18;
      int hh = h0 + r - 1, ww = w0 + c - 1;
      float v = 0.f;
      if (hh >= 0 && hh < HH && ww >= 0 && ww < WW) v = xp[hh * WW + ww];
      tile[r][c] = v;
    }
    __syncthreads();
    float t[9];
#pragma unroll
    for (int kh = 0; kh < 3; kh++)
#pragma unroll
      for (int kw = 0; kw < 3; kw++) t[kh * 3 + kw] = tile[ty + kh][tx + kw];
#pragma unroll
    for (int hd = 0; hd < 3; hd++) {
      const float* wp = wp3[hd] + ic * 9;
#pragma unroll
      for (int oc = 0; oc < 4; oc++) {
        float s = acc[hd * 4 + oc];
#pragma unroll
        for (int k = 0; k < 9; k++) s = fmaf(wp[oc * 32 * 9 + k], t[k], s);
        acc[hd * 4 + oc] = s;
      }
    }
  }
  const float* bb[3] = {b0p, b1p, b2p};
  int h = h0 + ty, wc = w0 + tx;
  float v[12];
  float* op = pre + h * WW + wc;
#pragma unroll
  for (int hd = 0; hd < 3; hd++)
#pragma unroll
    for (int oc = 0; oc < 4; oc++) {
      int i = hd * 4 + oc;
      v[i] = acc[i] + bb[hd][oc];
      op[i * HWSZ] = v[i];
    }
  // block reduction of the 12 channel sums
#pragma unroll
  for (int off = 32; off > 0; off >>= 1)
#pragma unroll
    for (int c = 0; c < 12; c++) v[c] += __shfl_down(v[c], off);
  __shared__ float part[4][12];
  int wave = threadIdx.x >> 6, lane = threadIdx.x & 63;
  if (lane == 0)
#pragma unroll
    for (int c = 0; c < 12; c++) part[wave][c] = v[c];
  __syncthreads();
  if (threadIdx.x < 12) {
    int c = threadIdx.x;
    float t = part[0][c] + part[1][c] + part[2][c] + part[3][c];
    atomicAdd(&S[c], t);
  }
}

// ------------- gates for all 3 heads: mean -> 1x1 relu -> 1x1 sigmoid -------------
__global__ void k_gate3(const float* __restrict__ S, const float* __restrict__ wa0,
                        const float* __restrict__ wa1, const float* __restrict__ wa2,
                        const float* __restrict__ wb0, const float* __restrict__ wb1,
                        const float* __restrict__ wb2, float* __restrict__ gate) {
  int t = threadIdx.x;
  if (t < 12) {
    int hd = t >> 2, o = t & 3;
    const float* wa = hd == 0 ? wa0 : (hd == 1 ? wa1 : wa2);
    const float* wb = hd == 0 ? wb0 : (hd == 1 ? wb1 : wb2);
    float m[4];
#pragma unroll
    for (int c = 0; c < 4; c++) m[c] = S[hd * 4 + c] * (1.0f / (float)HWSZ);
    float ga[4];
#pragma unroll
    for (int c = 0; c < 4; c++) {
      float s = 0.f;
#pragma unroll
      for (int j = 0; j < 4; j++) s = fmaf(wa[c * 4 + j], m[j], s);
      ga[c] = fmaxf(s, 0.f);
    }
    float s2 = 0.f;
#pragma unroll
    for (int c = 0; c < 4; c++) s2 = fmaf(wb[o * 4 + c], ga[c], s2);
    gate[t] = 1.f / (1.f + expf(-s2));
  }
}

// ------- fused: 3 box blurs (5/15/25) + softmax(gate*pre) + weighted combine -------
#define BT 32
#define RAD 12
#define SRCT (BT + 2 * RAD)  // 56
__global__ __launch_bounds__(256) void k_blurcombine(const float* __restrict__ src,
                                                     const float* __restrict__ pre,
                                                     const float* __restrict__ gate,
                                                     float* __restrict__ dst) {
  __shared__ float tile[SRCT][SRCT];
  __shared__ float hs[3][SRCT][BT];
  __shared__ float g[4];
  int h0 = blockIdx.y * BT - RAD, w0 = blockIdx.x * BT - RAD;
  if (threadIdx.x < 4) g[threadIdx.x] = gate[threadIdx.x];
  for (int idx = threadIdx.x; idx < SRCT * SRCT; idx += 256) {
    int r = idx / SRCT, c = idx % SRCT;
    int hh = h0 + r, ww = w0 + c;
    float v = 0.f;
    if (hh >= 0 && hh < HH && ww >= 0 && ww < WW) v = src[hh * WW + ww];
    tile[r][c] = v;
  }
  __syncthreads();
  // horizontal pass: SRCT rows x BT output cols
  for (int idx = threadIdx.x; idx < SRCT * BT; idx += 256) {
    int r = idx / BT, j = idx % BT;
    int cc = j + RAD;
    float s5 = 0.f;
#pragma unroll
    for (int d = -2; d <= 2; d++) s5 += tile[r][cc + d];
    float s15 = s5;
#pragma unroll
    for (int d = 3; d <= 7; d++) s15 += tile[r][cc + d] + tile[r][cc - d];
    float s25 = s15;
#pragma unroll
    for (int d = 8; d <= 12; d++) s25 += tile[r][cc + d] + tile[r][cc - d];
    hs[0][r][j] = s5;
    hs[1][r][j] = s15;
    hs[2][r][j] = s25;
  }
  __syncthreads();
  for (int p = threadIdx.x; p < BT * BT; p += 256) {
    int i = p / BT, j = p % BT;
    int rr = i + RAD;
    float b1 = 0.f;
#pragma unroll
    for (int d = -2; d <= 2; d++) b1 += hs[0][rr + d][j];
    float b2 = 0.f;
#pragma unroll
    for (int d = -7; d <= 7; d++) b2 += hs[1][rr + d][j];
    float b3 = 0.f;
#pragma unroll
    for (int d = -12; d <= 12; d++) b3 += hs[2][rr + d][j];
    b1 *= (1.f / 25.f);
    b2 *= (1.f / 225.f);
    b3 *= (1.f / 625.f);
    float b0 = tile[rr][j + RAD];
    int y = blockIdx.y * BT + i, x = blockIdx.x * BT + j;
    int pix = y * WW + x;
    float v[4];
#pragma unroll
    for (int c = 0; c < 4; c++) v[c] = pre[c * HWSZ + pix] * g[c];
    float mx = fmaxf(fmaxf(v[0], v[1]), fmaxf(v[2], v[3]));
    float e0 = expf(v[0] - mx), e1 = expf(v[1] - mx), e2 = expf(v[2] - mx),
          e3 = expf(v[3] - mx);
    float inv = 1.f / (e0 + e1 + e2 + e3);
    dst[pix] = (e0 * b0 + e1 * b1 + e2 * b2 + e3 * b3) * inv;
  }
}

extern "C" void kernel_launch(void* const* d_in, const int* in_sizes, int n_in,
                              void* d_out, int out_size, void* d_ws, size_t ws_size,
                              hipStream_t stream) {
  const float* x = (const float*)d_in[0];
  const float* w1 = (const float*)d_in[1];
  const float* b1 = (const float*)d_in[2];
  const float* a1 = (const float*)d_in[3];
  const float* w2 = (const float*)d_in[4];
  const float* b2 = (const float*)d_in[5];
  const float* a2 = (const float*)d_in[6];
  const float* w3 = (const float*)d_in[7];
  const float* b3 = (const float*)d_in[8];
  const float* a3 = (const float*)d_in[9];
  const float* hw[3] = {(const float*)d_in[10], (const float*)d_in[14], (const float*)d_in[18]};
  const float* hb[3] = {(const float*)d_in[11], (const float*)d_in[15], (const float*)d_in[19]};
  const float* caa[3] = {(const float*)d_in[12], (const float*)d_in[16], (const float*)d_in[20]};
  const float* cab[3] = {(const float*)d_in[13], (const float*)d_in[17], (const float*)d_in[21]};

  float* ws = (float*)d_ws;
  // per-image reusable buffers: total ~116 MB
  float* t1 = ws;                       // 32*HW   = 8,388,608 floats (conv1 out, conv3 out)
  float* t2 = t1 + 32 * HWSZ;           // 64*HW   = 16,777,216 floats (conv2 out)
  float* pre = t2 + 64 * HWSZ;          // 12*HW   = 3,145,728 floats (3 heads x 4ch)
  float* out1 = pre + 12 * HWSZ;        // HW
  float* out2 = out1 + HWSZ;            // HW
  float* S = out2 + HWSZ;               // 12 floats (channel sums, 3 heads)
  float* gate = S + 16;                 // 12 floats

  dim3 blk(256);
  dim3 gconv(WW / TS, HH / TS, 1);
  dim3 gbc(WW / BT, HH / BT, 1);

  for (int b = 0; b < NB; b++) {
    const float* xb = x + (size_t)b * HWSZ;
    k_conv1<<<gconv, blk, 0, stream>>>(xb, w1, b1, a1, t1);
    k_conv<32, 64><<<gconv, blk, 0, stream>>>(t1, w2, b2, a2, t2);
    k_conv<64, 32><<<gconv, blk, 0, stream>>>(t2, w3, b3, a3, t1);
    hipMemsetAsync(S, 0, 12 * sizeof(float), stream);
    k_headconv3<<<gconv, blk, 0, stream>>>(t1, hw[0], hw[1], hw[2], hb[0], hb[1],
                                           hb[2], pre, S);
    k_gate3<<<1, 64, 0, stream>>>(S, caa[0], caa[1], caa[2], cab[0], cab[1], cab[2],
                                  gate);
    float* outb = (float*)d_out + (size_t)b * HWSZ;
    k_blurcombine<<<gbc, blk, 0, stream>>>(xb, pre + 0 * 4 * HWSZ, gate + 0, out1);
    k_blurcombine<<<gbc, blk, 0, stream>>>(out1, pre + 1 * 4 * HWSZ, gate + 4, out2);
    k_blurcombine<<<gbc, blk, 0, stream>>>(out2, pre + 2 * 4 * HWSZ, gate + 8, outb);
  }
}

// Round 3
// 1670.936 us; speedup vs baseline: 2.5423x; 2.5423x over previous
//
#include <hip/hip_runtime.h>

#define HH 512
#define WW 512
#define NB 8
#define HWSZ (HH * WW)
#define PW 514  // zero-padded spatial dim for NHWC activation buffers

typedef float f32x4 __attribute__((ext_vector_type(4)));
typedef short bf16x8 __attribute__((ext_vector_type(8)));

__device__ __forceinline__ unsigned short f2bf(float f) {
  union { float f; unsigned u; } v; v.f = f;
  unsigned r = v.u + 0x7FFFu + ((v.u >> 16) & 1u);
  return (unsigned short)(r >> 16);
}
__device__ __forceinline__ float bf2f(unsigned u16) {
  union { unsigned u; float f; } v; v.u = u16 << 16;
  return v.f;
}

// ---- weight repack: [OC][IC][3][3] fp32 -> [9][OC][IC] bf16 ----
__global__ void k_prepw(const float* __restrict__ w, unsigned short* __restrict__ dst,
                        int OC, int IC) {
  int i = blockIdx.x * 256 + threadIdx.x;
  if (i >= 9 * OC * IC) return;
  int ic = i % IC;
  int t = i / IC;
  int oc = t % OC;
  int k = t / OC;
  dst[i] = f2bf(w[(oc * IC + ic) * 9 + k]);
}

// ---- head weights: three [4][32][3][3] -> [9][16][32] bf16 (oc 12..15 zero) ----
__global__ void k_prepw_head(const float* __restrict__ w0, const float* __restrict__ w1,
                             const float* __restrict__ w2, unsigned short* __restrict__ dst) {
  int i = blockIdx.x * 256 + threadIdx.x;
  if (i >= 9 * 16 * 32) return;
  int ic = i & 31;
  int t = i >> 5;
  int oc = t & 15;
  int k = t >> 4;
  float v = 0.f;
  if (oc < 12) {
    const float* w = oc < 4 ? w0 : (oc < 8 ? w1 : w2);
    int o = oc & 3;
    v = w[(o * 32 + ic) * 9 + k];
  }
  dst[i] = f2bf(v);
}

// ---- zero the spatial pad ring of a padded NHWC buffer ----
__global__ void k_zeropad(unsigned short* __restrict__ buf, int IC) {
  int i = blockIdx.x * 256 + threadIdx.x;
  int rowElems = PW * IC;
  if (i < 2 * rowElems) {  // rows 0 and 513 (full)
    int r = (i < rowElems) ? 0 : (PW - 1);
    int j = i % rowElems;
    buf[r * rowElems + j] = 0;
    return;
  }
  i -= 2 * rowElems;
  int tot = 512 * 2 * IC;  // cols 0 and 513 for rows 1..512
  if (i < tot) {
    int r = 1 + i / (2 * IC);
    int j = i % (2 * IC);
    int c = (j < IC) ? 0 : (PW - 1);
    buf[(r * PW + c) * IC + (j % IC)] = 0;
  }
}

// ---- conv1: 1->32, VALU, fp32 in -> padded NHWC bf16 out ----
__global__ __launch_bounds__(256) void k_conv1(const float* __restrict__ x,
                                               const float* __restrict__ w,
                                               const float* __restrict__ bias,
                                               const float* __restrict__ a_ptr,
                                               unsigned short* __restrict__ out) {
  int pix = blockIdx.x * 256 + threadIdx.x;
  int h = pix >> 9, wc = pix & 511;
  float t[9];
#pragma unroll
  for (int dh = 0; dh < 3; dh++)
#pragma unroll
    for (int dw = 0; dw < 3; dw++) {
      int hh = h + dh - 1, ww = wc + dw - 1;
      t[dh * 3 + dw] =
          (hh >= 0 && hh < HH && ww >= 0 && ww < WW) ? x[hh * WW + ww] : 0.f;
    }
  float a = a_ptr[0];
  unsigned pk[16];
#pragma unroll
  for (int oc = 0; oc < 32; oc++) {
    float s = bias[oc];
#pragma unroll
    for (int k = 0; k < 9; k++) s = fmaf(w[oc * 9 + k], t[k], s);
    s = s >= 0.f ? s : a * s;
    unsigned short b = f2bf(s);
    if (oc & 1)
      pk[oc >> 1] |= ((unsigned)b) << 16;
    else
      pk[oc >> 1] = b;
  }
  uint4* op = (uint4*)(out + ((h + 1) * PW + (wc + 1)) * 32);
#pragma unroll
  for (int q = 0; q < 4; q++) op[q] = *(uint4*)&pk[q * 4];
}

// ---- MFMA implicit-GEMM 3x3 conv: padded NHWC bf16 -> padded NHWC bf16, bias+prelu ----
template <int IC, int OC, int NBLK>
__global__ __launch_bounds__(256) void k_convm(const unsigned short* __restrict__ in,
                                               const unsigned short* __restrict__ wp,
                                               const float* __restrict__ bias,
                                               const float* __restrict__ a_ptr,
                                               unsigned short* __restrict__ out) {
  constexpr int MT = OC / 16;      // M tiles (16 oc each)
  constexpr int NGW = 4 / MT;      // wave groups along N
  constexpr int NPW_ = NBLK / NGW; // pixels per wave
  constexpr int NT = NPW_ / 16;    // N subtiles per wave
  constexpr int KS = IC / 32;      // K steps per (dh,dw)
  const int tid = threadIdx.x, lane = tid & 63, wid = tid >> 6;
  const int mt = wid % MT, ng = wid / MT;
  const int l15 = lane & 15, q = lane >> 4, icb = q * 8;
  const int pix0 = blockIdx.x * NBLK;
  const int h = pix0 >> 9;
  const int wloc = (pix0 & 511) + ng * NPW_;

  bf16x8 afr[9 * KS];
#pragma unroll
  for (int k9 = 0; k9 < 9; k9++)
#pragma unroll
    for (int ks = 0; ks < KS; ks++)
      afr[k9 * KS + ks] =
          *(const bf16x8*)(wp + (k9 * OC + mt * 16 + l15) * IC + ks * 32 + icb);

  f32x4 acc[NT];
#pragma unroll
  for (int i = 0; i < NT; i++)
#pragma unroll
    for (int j = 0; j < 4; j++) acc[i][j] = 0.f;

#pragma unroll
  for (int dh = 0; dh < 3; dh++) {
    const unsigned short* rbase = in + (h + dh) * (PW * IC);
#pragma unroll
    for (int dw = 0; dw < 3; dw++) {
#pragma unroll
      for (int ks = 0; ks < KS; ks++) {
        bf16x8 a = afr[(dh * 3 + dw) * KS + ks];
#pragma unroll
        for (int nt = 0; nt < NT; nt++) {
          int col = wloc + nt * 16 + l15 + dw;  // padded col index
          bf16x8 b = *(const bf16x8*)(rbase + col * IC + ks * 32 + icb);
          acc[nt] = __builtin_amdgcn_mfma_f32_16x16x32_bf16(a, b, acc[nt], 0, 0, 0);
        }
      }
    }
  }

  const float alpha = a_ptr[0];
  const int ocb = mt * 16 + q * 4;
  f32x4 bv = *(const f32x4*)(bias + ocb);
#pragma unroll
  for (int nt = 0; nt < NT; nt++) {
    int col = wloc + nt * 16 + l15 + 1;
    unsigned short* op = out + ((h + 1) * PW + col) * OC + ocb;
    float v[4];
#pragma unroll
    for (int r = 0; r < 4; r++) {
      float s = acc[nt][r] + bv[r];
      v[r] = s >= 0.f ? s : alpha * s;
    }
    uint2 pk;
    pk.x = (unsigned)f2bf(v[0]) | ((unsigned)f2bf(v[1]) << 16);
    pk.y = (unsigned)f2bf(v[2]) | ((unsigned)f2bf(v[3]) << 16);
    *(uint2*)op = pk;
  }
}

// ---- fused 3-head conv 32->16(12 real): pre [HW][16] bf16 + channel sums ----
__global__ __launch_bounds__(256) void k_headm(const unsigned short* __restrict__ in,
                                               const unsigned short* __restrict__ wp,
                                               const float* __restrict__ hb0,
                                               const float* __restrict__ hb1,
                                               const float* __restrict__ hb2,
                                               unsigned short* __restrict__ pre,
                                               float* __restrict__ S) {
  const int tid = threadIdx.x, lane = tid & 63, wid = tid >> 6;
  const int l15 = lane & 15, q = lane >> 4, icb = q * 8;
  const int pix0 = blockIdx.x * 256;
  const int h = pix0 >> 9;
  const int wloc = (pix0 & 511) + wid * 64;

  bf16x8 afr[9];
#pragma unroll
  for (int k9 = 0; k9 < 9; k9++)
    afr[k9] = *(const bf16x8*)(wp + (k9 * 16 + l15) * 32 + icb);

  f32x4 acc[4];
#pragma unroll
  for (int i = 0; i < 4; i++)
#pragma unroll
    for (int j = 0; j < 4; j++) acc[i][j] = 0.f;

#pragma unroll
  for (int dh = 0; dh < 3; dh++) {
    const unsigned short* rbase = in + (h + dh) * (PW * 32);
#pragma unroll
    for (int dw = 0; dw < 3; dw++) {
      bf16x8 a = afr[dh * 3 + dw];
#pragma unroll
      for (int nt = 0; nt < 4; nt++) {
        int col = wloc + nt * 16 + l15 + dw;
        bf16x8 b = *(const bf16x8*)(rbase + col * 32 + icb);
        acc[nt] = __builtin_amdgcn_mfma_f32_16x16x32_bf16(a, b, acc[nt], 0, 0, 0);
      }
    }
  }

  float bs[4];
#pragma unroll
  for (int r = 0; r < 4; r++) {
    int oc = q * 4 + r;
    bs[r] = oc < 4 ? hb0[oc] : (oc < 8 ? hb1[oc - 4] : (oc < 12 ? hb2[oc - 8] : 0.f));
  }
  float csum[4] = {0.f, 0.f, 0.f, 0.f};
#pragma unroll
  for (int nt = 0; nt < 4; nt++) {
    int pix = pix0 + wid * 64 + nt * 16 + l15;
    float v[4];
#pragma unroll
    for (int r = 0; r < 4; r++) {
      v[r] = acc[nt][r] + bs[r];
      csum[r] += v[r];
    }
    uint2 pk;
    pk.x = (unsigned)f2bf(v[0]) | ((unsigned)f2bf(v[1]) << 16);
    pk.y = (unsigned)f2bf(v[2]) | ((unsigned)f2bf(v[3]) << 16);
    *(uint2*)(pre + (size_t)pix * 16 + q * 4) = pk;
  }
  // sum over the 16 pixels within each quarter-wave
#pragma unroll
  for (int d = 1; d < 16; d <<= 1)
#pragma unroll
    for (int r = 0; r < 4; r++) csum[r] += __shfl_xor(csum[r], d, 64);
  __shared__ float part[4][4][4];
  if (l15 == 0)
#pragma unroll
    for (int r = 0; r < 4; r++) part[wid][q][r] = csum[r];
  __syncthreads();
  if (tid < 12) {
    int oc = tid;
    float s = part[0][oc >> 2][oc & 3] + part[1][oc >> 2][oc & 3] +
              part[2][oc >> 2][oc & 3] + part[3][oc >> 2][oc & 3];
    atomicAdd(&S[oc], s);
  }
}

// ---- gates for all 3 heads ----
__global__ void k_gate3(const float* __restrict__ S, const float* __restrict__ wa0,
                        const float* __restrict__ wa1, const float* __restrict__ wa2,
                        const float* __restrict__ wb0, const float* __restrict__ wb1,
                        const float* __restrict__ wb2, float* __restrict__ gate) {
  int t = threadIdx.x;
  if (t < 12) {
    int hd = t >> 2, o = t & 3;
    const float* wa = hd == 0 ? wa0 : (hd == 1 ? wa1 : wa2);
    const float* wb = hd == 0 ? wb0 : (hd == 1 ? wb1 : wb2);
    float m[4];
#pragma unroll
    for (int c = 0; c < 4; c++) m[c] = S[hd * 4 + c] * (1.0f / (float)HWSZ);
    float ga[4];
#pragma unroll
    for (int c = 0; c < 4; c++) {
      float s = 0.f;
#pragma unroll
      for (int j = 0; j < 4; j++) s = fmaf(wa[c * 4 + j], m[j], s);
      ga[c] = fmaxf(s, 0.f);
    }
    float s2 = 0.f;
#pragma unroll
    for (int c = 0; c < 4; c++) s2 = fmaf(wb[o * 4 + c], ga[c], s2);
    gate[t] = 1.f / (1.f + expf(-s2));
  }
}

// ---- fused: 3 box blurs + softmax(gate*pre) + weighted combine ----
#define BT 32
#define RAD 12
#define SRCT (BT + 2 * RAD)  // 56
__global__ __launch_bounds__(256) void k_blurcombine(const float* __restrict__ src,
                                                     const unsigned short* __restrict__ pre,
                                                     const float* __restrict__ gate,
                                                     float* __restrict__ dst) {
  __shared__ float tile[SRCT][SRCT];
  __shared__ float hs[3][SRCT][BT];
  __shared__ float g[4];
  int h0 = blockIdx.y * BT - RAD, w0 = blockIdx.x * BT - RAD;
  if (threadIdx.x < 4) g[threadIdx.x] = gate[threadIdx.x];
  for (int idx = threadIdx.x; idx < SRCT * SRCT; idx += 256) {
    int r = idx / SRCT, c = idx % SRCT;
    int hh = h0 + r, ww = w0 + c;
    float v = 0.f;
    if (hh >= 0 && hh < HH && ww >= 0 && ww < WW) v = src[hh * WW + ww];
    tile[r][c] = v;
  }
  __syncthreads();
  for (int idx = threadIdx.x; idx < SRCT * BT; idx += 256) {
    int r = idx / BT, j = idx % BT;
    int cc = j + RAD;
    float s5 = 0.f;
#pragma unroll
    for (int d = -2; d <= 2; d++) s5 += tile[r][cc + d];
    float s15 = s5;
#pragma unroll
    for (int d = 3; d <= 7; d++) s15 += tile[r][cc + d] + tile[r][cc - d];
    float s25 = s15;
#pragma unroll
    for (int d = 8; d <= 12; d++) s25 += tile[r][cc + d] + tile[r][cc - d];
    hs[0][r][j] = s5;
    hs[1][r][j] = s15;
    hs[2][r][j] = s25;
  }
  __syncthreads();
  for (int p = threadIdx.x; p < BT * BT; p += 256) {
    int i = p / BT, j = p % BT;
    int rr = i + RAD;
    float b1 = 0.f;
#pragma unroll
    for (int d = -2; d <= 2; d++) b1 += hs[0][rr + d][j];
    float b2 = 0.f;
#pragma unroll
    for (int d = -7; d <= 7; d++) b2 += hs[1][rr + d][j];
    float b3 = 0.f;
#pragma unroll
    for (int d = -12; d <= 12; d++) b3 += hs[2][rr + d][j];
    b1 *= (1.f / 25.f);
    b2 *= (1.f / 225.f);
    b3 *= (1.f / 625.f);
    float b0 = tile[rr][j + RAD];
    int y = blockIdx.y * BT + i, x = blockIdx.x * BT + j;
    int pix = y * WW + x;
    uint2 pk = *(const uint2*)(pre + (size_t)pix * 16);
    float v[4];
    v[0] = bf2f(pk.x & 0xffffu) * g[0];
    v[1] = bf2f(pk.x >> 16) * g[1];
    v[2] = bf2f(pk.y & 0xffffu) * g[2];
    v[3] = bf2f(pk.y >> 16) * g[3];
    float mx = fmaxf(fmaxf(v[0], v[1]), fmaxf(v[2], v[3]));
    float e0 = expf(v[0] - mx), e1 = expf(v[1] - mx), e2 = expf(v[2] - mx),
          e3 = expf(v[3] - mx);
    float inv = 1.f / (e0 + e1 + e2 + e3);
    dst[pix] = (e0 * b0 + e1 * b1 + e2 * b2 + e3 * b3) * inv;
  }
}

extern "C" void kernel_launch(void* const* d_in, const int* in_sizes, int n_in,
                              void* d_out, int out_size, void* d_ws, size_t ws_size,
                              hipStream_t stream) {
  const float* x = (const float*)d_in[0];
  const float* w1 = (const float*)d_in[1];
  const float* b1 = (const float*)d_in[2];
  const float* a1 = (const float*)d_in[3];
  const float* w2 = (const float*)d_in[4];
  const float* b2 = (const float*)d_in[5];
  const float* a2 = (const float*)d_in[6];
  const float* w3 = (const float*)d_in[7];
  const float* b3 = (const float*)d_in[8];
  const float* a3 = (const float*)d_in[9];
  const float* hw[3] = {(const float*)d_in[10], (const float*)d_in[14], (const float*)d_in[18]};
  const float* hb[3] = {(const float*)d_in[11], (const float*)d_in[15], (const float*)d_in[19]};
  const float* caa[3] = {(const float*)d_in[12], (const float*)d_in[16], (const float*)d_in[20]};
  const float* cab[3] = {(const float*)d_in[13], (const float*)d_in[17], (const float*)d_in[21]};

  // workspace layout (bytes), 64B-aligned chunks; total ~62 MB
  char* base = (char*)d_ws;
  size_t off = 0;
  auto alloc = [&](size_t bytes) {
    char* p = base + off;
    off = (off + bytes + 63) & ~(size_t)63;
    return p;
  };
  unsigned short* t1 = (unsigned short*)alloc((size_t)PW * PW * 32 * 2);
  unsigned short* t2 = (unsigned short*)alloc((size_t)PW * PW * 64 * 2);
  unsigned short* pre = (unsigned short*)alloc((size_t)HWSZ * 16 * 2);
  unsigned short* wp2 = (unsigned short*)alloc(9 * 64 * 32 * 2);
  unsigned short* wp3 = (unsigned short*)alloc(9 * 64 * 32 * 2);
  unsigned short* wph = (unsigned short*)alloc(9 * 16 * 32 * 2);
  float* out1 = (float*)alloc((size_t)HWSZ * 4);
  float* out2 = (float*)alloc((size_t)HWSZ * 4);
  float* S = (float*)alloc(64);
  float* gate = (float*)alloc(64);

  dim3 blk(256);
  // one-time per launch: weight repack + pad-ring zeroing
  k_prepw<<<(9 * 64 * 32 + 255) / 256, blk, 0, stream>>>(w2, wp2, 64, 32);
  k_prepw<<<(9 * 64 * 32 + 255) / 256, blk, 0, stream>>>(w3, wp3, 32, 64);
  k_prepw_head<<<(9 * 16 * 32 + 255) / 256, blk, 0, stream>>>(hw[0], hw[1], hw[2], wph);
  k_zeropad<<<(2 * PW * 32 + 2 * 512 * 32 + 255) / 256, blk, 0, stream>>>(t1, 32);
  k_zeropad<<<(2 * PW * 64 + 2 * 512 * 64 + 255) / 256, blk, 0, stream>>>(t2, 64);

  dim3 gbc(WW / BT, HH / BT, 1);
  for (int b = 0; b < NB; b++) {
    const float* xb = x + (size_t)b * HWSZ;
    k_conv1<<<HWSZ / 256, blk, 0, stream>>>(xb, w1, b1, a1, t1);
    k_convm<32, 64, 128><<<HWSZ / 128, blk, 0, stream>>>(t1, wp2, b2, a2, t2);
    k_convm<64, 32, 128><<<HWSZ / 128, blk, 0, stream>>>(t2, wp3, b3, a3, t1);
    hipMemsetAsync(S, 0, 12 * sizeof(float), stream);
    k_headm<<<HWSZ / 256, blk, 0, stream>>>(t1, wph, hb[0], hb[1], hb[2], pre, S);
    k_gate3<<<1, 64, 0, stream>>>(S, caa[0], caa[1], caa[2], cab[0], cab[1], cab[2], gate);
    float* outb = (float*)d_out + (size_t)b * HWSZ;
    k_blurcombine<<<gbc, blk, 0, stream>>>(xb, pre + 0, gate + 0, out1);
    k_blurcombine<<<gbc, blk, 0, stream>>>(out1, pre + 4, gate + 4, out2);
    k_blurcombine<<<gbc, blk, 0, stream>>>(out2, pre + 8, gate + 8, outb);
  }
}

// Round 4
// 1195.720 us; speedup vs baseline: 3.5527x; 1.3974x over previous
//
#include <hip/hip_runtime.h>

#define HH 512
#define WW 512
#define NB 8
#define HWSZ (HH * WW)
#define PW 514  // zero-padded spatial dim for NHWC activation buffers

typedef float f32x4 __attribute__((ext_vector_type(4)));
typedef float f32x16 __attribute__((ext_vector_type(16)));
typedef short bf16x8 __attribute__((ext_vector_type(8)));

__device__ __forceinline__ unsigned short f2bf(float f) {
  union { float f; unsigned u; } v; v.f = f;
  unsigned r = v.u + 0x7FFFu + ((v.u >> 16) & 1u);
  return (unsigned short)(r >> 16);
}
__device__ __forceinline__ float bf2f(unsigned u16) {
  union { unsigned u; float f; } v; v.u = u16 << 16;
  return v.f;
}

// ---- zero the spatial pad ring of a padded NHWC buffer (element i of range) ----
__device__ __forceinline__ void zp(unsigned short* buf, int IC, int i) {
  int rowElems = PW * IC;
  if (i < 2 * rowElems) {  // rows 0 and 513 (full)
    int r = (i < rowElems) ? 0 : (PW - 1);
    int j = i % rowElems;
    buf[r * rowElems + j] = 0;
    return;
  }
  i -= 2 * rowElems;
  int r = 1 + i / (2 * IC);
  int j = i % (2 * IC);
  int c = (j < IC) ? 0 : (PW - 1);
  buf[(r * PW + c) * IC + (j % IC)] = 0;
}

// ---- fused one-time prep: weight repacks + pad-ring zero + S zero ----
__global__ __launch_bounds__(256) void k_prep(const float* __restrict__ w2,
                                              const float* __restrict__ w3,
                                              const float* __restrict__ h0,
                                              const float* __restrict__ h1,
                                              const float* __restrict__ h2,
                                              unsigned short* __restrict__ wp2,
                                              unsigned short* __restrict__ wp3,
                                              unsigned short* __restrict__ wph,
                                              unsigned short* __restrict__ t1,
                                              unsigned short* __restrict__ t2,
                                              float* __restrict__ S) {
  int i = blockIdx.x * 256 + threadIdx.x;
  const int N1 = 9 * 64 * 32;
  const int N2 = N1 + 9 * 32 * 64;
  const int N3 = N2 + 9 * 16 * 32;
  const int NZ1 = 2 * PW * 32 + 2 * 512 * 32;
  const int N4 = N3 + NZ1;
  const int NZ2 = 2 * PW * 64 + 2 * 512 * 64;
  const int N5 = N4 + NZ2;
  const int N6 = N5 + 128;
  if (i < N1) {  // w2 [64][32][3][3] -> [9][64][32]
    int ic = i & 31, t = i >> 5, oc = t & 63, k = t >> 6;
    wp2[i] = f2bf(w2[(oc * 32 + ic) * 9 + k]);
  } else if (i < N2) {  // w3 [32][64][3][3] -> [9][32][64]
    int j = i - N1;
    int ic = j & 63, t = j >> 6, oc = t & 31, k = t >> 5;
    wp3[j] = f2bf(w3[(oc * 64 + ic) * 9 + k]);
  } else if (i < N3) {  // heads -> [9][16][32], oc 12..15 zero
    int j = i - N2;
    int ic = j & 31, t = j >> 5, oc = t & 15, k = t >> 4;
    float v = 0.f;
    if (oc < 12) {
      const float* w = oc < 4 ? h0 : (oc < 8 ? h1 : h2);
      v = w[((oc & 3) * 32 + ic) * 9 + k];
    }
    wph[j] = f2bf(v);
  } else if (i < N4) {
    zp(t1, 32, i - N3);
  } else if (i < N5) {
    zp(t2, 64, i - N4);
  } else if (i < N6) {
    S[i - N5] = 0.f;
  }
}

// ---- conv1: 1->32, VALU, fp32 in -> padded NHWC bf16 out ----
__global__ __launch_bounds__(256) void k_conv1(const float* __restrict__ x,
                                               const float* __restrict__ w,
                                               const float* __restrict__ bias,
                                               const float* __restrict__ a_ptr,
                                               unsigned short* __restrict__ out) {
  int pix = blockIdx.x * 256 + threadIdx.x;
  int h = pix >> 9, wc = pix & 511;
  float t[9];
#pragma unroll
  for (int dh = 0; dh < 3; dh++)
#pragma unroll
    for (int dw = 0; dw < 3; dw++) {
      int hh = h + dh - 1, ww = wc + dw - 1;
      t[dh * 3 + dw] =
          (hh >= 0 && hh < HH && ww >= 0 && ww < WW) ? x[hh * WW + ww] : 0.f;
    }
  float a = a_ptr[0];
  unsigned pk[16];
#pragma unroll
  for (int oc = 0; oc < 32; oc++) {
    float s = bias[oc];
#pragma unroll
    for (int k = 0; k < 9; k++) s = fmaf(w[oc * 9 + k], t[k], s);
    s = s >= 0.f ? s : a * s;
    unsigned short b = f2bf(s);
    if (oc & 1)
      pk[oc >> 1] |= ((unsigned)b) << 16;
    else
      pk[oc >> 1] = b;
  }
  uint4* op = (uint4*)(out + ((size_t)(h + 1) * PW + (wc + 1)) * 32);
#pragma unroll
  for (int q = 0; q < 4; q++) op[q] = *(uint4*)&pk[q * 4];
}

// ---- LDS-staged MFMA 3x3 conv (32x32x16), padded NHWC bf16 -> same, bias+prelu ----
// Block: 2 output rows x 64 cols, 4 waves; wave = (rowsel, 32-px half); mt-loop over OC/32.
template <int IC, int OC>
__global__ __launch_bounds__(256) void k_convm(const unsigned short* __restrict__ in,
                                               const unsigned short* __restrict__ wp,
                                               const float* __restrict__ bias,
                                               const float* __restrict__ a_ptr,
                                               unsigned short* __restrict__ out) {
  constexpr int KS = IC / 16;        // K-steps per tap
  constexpr int MT = OC / 32;        // M tiles
  constexpr int NCH = IC / 8;        // 16B chunks per pixel
  constexpr int LNC = (IC == 32) ? 2 : 3;
  constexpr int SSH = (IC == 32) ? 1 : 0;  // swizzle shift (skip parity bit when px=16 words)
  constexpr int SMK = NCH - 1;
  __shared__ short lds[4 * 68 * IC];
  const int tid = threadIdx.x;
  const int r0 = blockIdx.y * 2, c0 = blockIdx.x * 64;

  // stage 4 rows x 66 cols, swizzled 16B chunks
  constexpr int TOT = 4 * 66 * NCH;
  for (int i = tid; i < TOT; i += 256) {
    int ch = i & SMK;
    int p = i >> LNC;
    int prow = p / 66;
    int pcol = p - prow * 66;
    int pl = prow * 68 + pcol;
    uint4 v = *(const uint4*)(in + ((size_t)(r0 + prow) * PW + (c0 + pcol)) * IC + ch * 8);
    *(uint4*)(&lds[(pl * NCH + (ch ^ ((pl >> SSH) & SMK))) * 8]) = v;
  }
  __syncthreads();

  const int lane = tid & 63, wid = tid >> 6;
  const int l31 = lane & 31, h16 = lane >> 5;
  const int rowsel = wid >> 1, half = wid & 1;

  f32x16 acc[MT];
#pragma unroll
  for (int mt = 0; mt < MT; mt++)
#pragma unroll
    for (int j = 0; j < 16; j++) acc[mt][j] = 0.f;

#pragma unroll
  for (int dh = 0; dh < 3; dh++) {
    bf16x8 af[3][KS][MT];
#pragma unroll
    for (int dw = 0; dw < 3; dw++)
#pragma unroll
      for (int ks = 0; ks < KS; ks++)
#pragma unroll
        for (int mt = 0; mt < MT; mt++)
          af[dw][ks][mt] = *(const bf16x8*)(
              wp + (((dh * 3 + dw) * OC + mt * 32 + l31) * IC + ks * 16 + h16 * 8));
    const int lrow = (rowsel + dh) * 68;
#pragma unroll
    for (int dw = 0; dw < 3; dw++) {
      const int pl = lrow + half * 32 + l31 + dw;
#pragma unroll
      for (int ks = 0; ks < KS; ks++) {
        int blk = (ks * 2 + h16) ^ ((pl >> SSH) & SMK);
        bf16x8 b = *(const bf16x8*)(&lds[(pl * NCH + blk) * 8]);
#pragma unroll
        for (int mt = 0; mt < MT; mt++)
          acc[mt] = __builtin_amdgcn_mfma_f32_32x32x16_bf16(af[dw][ks][mt], b,
                                                            acc[mt], 0, 0, 0);
      }
    }
  }

  const float alpha = a_ptr[0];
  const int orow = r0 + rowsel + 1, ocol = c0 + half * 32 + l31 + 1;
  unsigned short* op = out + ((size_t)orow * PW + ocol) * OC;
#pragma unroll
  for (int mt = 0; mt < MT; mt++)
#pragma unroll
    for (int g = 0; g < 4; g++) {
      int oc0 = mt * 32 + g * 8 + h16 * 4;
      float v[4];
#pragma unroll
      for (int j = 0; j < 4; j++) {
        float s = acc[mt][g * 4 + j] + bias[oc0 + j];
        v[j] = s >= 0.f ? s : alpha * s;
      }
      uint2 pk;
      pk.x = (unsigned)f2bf(v[0]) | ((unsigned)f2bf(v[1]) << 16);
      pk.y = (unsigned)f2bf(v[2]) | ((unsigned)f2bf(v[3]) << 16);
      *(uint2*)(op + oc0) = pk;
    }
}

// ---- fused 3-head conv 32->16(12 real), LDS-staged 16x16x32; pre + channel sums ----
// Block: 2 rows x 128 cols; wave = (rowsel, 64-px half), 4 N-tiles of 16 px.
__global__ __launch_bounds__(256) void k_headm(const unsigned short* __restrict__ in,
                                               const unsigned short* __restrict__ wp,
                                               const float* __restrict__ hb0,
                                               const float* __restrict__ hb1,
                                               const float* __restrict__ hb2,
                                               unsigned short* __restrict__ pre,
                                               float* __restrict__ S) {
  __shared__ short lds[4 * 132 * 32];
  const int tid = threadIdx.x;
  const int r0 = blockIdx.y * 2, c0 = blockIdx.x * 128;
  for (int i = tid; i < 4 * 130 * 4; i += 256) {
    int ch = i & 3;
    int p = i >> 2;
    int prow = p / 130;
    int pcol = p - prow * 130;
    int pl = prow * 132 + pcol;
    uint4 v = *(const uint4*)(in + ((size_t)(r0 + prow) * PW + (c0 + pcol)) * 32 + ch * 8);
    *(uint4*)(&lds[(pl * 4 + (ch ^ ((pl >> 1) & 3))) * 8]) = v;
  }
  __syncthreads();

  const int lane = tid & 63, wid = tid >> 6;
  const int l15 = lane & 15, q = lane >> 4;
  const int rowsel = wid >> 1, half = wid & 1;

  f32x4 acc[4];
#pragma unroll
  for (int i = 0; i < 4; i++)
#pragma unroll
    for (int j = 0; j < 4; j++) acc[i][j] = 0.f;

#pragma unroll
  for (int dh = 0; dh < 3; dh++) {
    bf16x8 af[3];
#pragma unroll
    for (int dw = 0; dw < 3; dw++)
      af[dw] = *(const bf16x8*)(wp + ((dh * 3 + dw) * 16 + l15) * 32 + q * 8);
    const int lrow = (rowsel + dh) * 132;
#pragma unroll
    for (int dw = 0; dw < 3; dw++) {
#pragma unroll
      for (int nt = 0; nt < 4; nt++) {
        int pl = lrow + half * 64 + nt * 16 + l15 + dw;
        int blk = q ^ ((pl >> 1) & 3);
        bf16x8 b = *(const bf16x8*)(&lds[(pl * 4 + blk) * 8]);
        acc[nt] = __builtin_amdgcn_mfma_f32_16x16x32_bf16(af[dw], b, acc[nt], 0, 0, 0);
      }
    }
  }

  float bs[4];
#pragma unroll
  for (int r = 0; r < 4; r++) {
    int oc = q * 4 + r;
    bs[r] = oc < 4 ? hb0[oc] : (oc < 8 ? hb1[oc - 4] : (oc < 12 ? hb2[oc - 8] : 0.f));
  }
  float csum[4] = {0.f, 0.f, 0.f, 0.f};
  const int orow = r0 + rowsel;
#pragma unroll
  for (int nt = 0; nt < 4; nt++) {
    int pcol = c0 + half * 64 + nt * 16 + l15;
    int pix = orow * 512 + pcol;
    float v[4];
#pragma unroll
    for (int r = 0; r < 4; r++) {
      v[r] = acc[nt][r] + bs[r];
      csum[r] += v[r];
    }
    uint2 pk;
    pk.x = (unsigned)f2bf(v[0]) | ((unsigned)f2bf(v[1]) << 16);
    pk.y = (unsigned)f2bf(v[2]) | ((unsigned)f2bf(v[3]) << 16);
    *(uint2*)(pre + (size_t)pix * 16 + q * 4) = pk;
  }
#pragma unroll
  for (int d = 1; d < 16; d <<= 1)
#pragma unroll
    for (int r = 0; r < 4; r++) csum[r] += __shfl_xor(csum[r], d, 64);
  __shared__ float part[4][4][4];
  if (l15 == 0)
#pragma unroll
    for (int r = 0; r < 4; r++) part[wid][q][r] = csum[r];
  __syncthreads();
  if (tid < 12) {
    int oc = tid;
    float s = part[0][oc >> 2][oc & 3] + part[1][oc >> 2][oc & 3] +
              part[2][oc >> 2][oc & 3] + part[3][oc >> 2][oc & 3];
    atomicAdd(&S[oc], s);
  }
}

// ---- fused: gate + 3 box blurs + softmax(gate*pre) + weighted combine ----
#define BT 32
#define RAD 12
#define SRCT (BT + 2 * RAD)  // 56
__global__ __launch_bounds__(256) void k_blurcombine(const float* __restrict__ src,
                                                     const unsigned short* __restrict__ pre,
                                                     const float* __restrict__ S4,
                                                     const float* __restrict__ wa,
                                                     const float* __restrict__ wb,
                                                     float* __restrict__ dst) {
  __shared__ float tile[SRCT][SRCT];
  __shared__ float hs[3][SRCT][BT];
  __shared__ float g[4];
  int h0 = blockIdx.y * BT - RAD, w0 = blockIdx.x * BT - RAD;
  if (threadIdx.x < 4) {
    int o = threadIdx.x;
    float m[4], ga[4];
#pragma unroll
    for (int c = 0; c < 4; c++) m[c] = S4[c] * (1.0f / (float)HWSZ);
#pragma unroll
    for (int c = 0; c < 4; c++) {
      float s = 0.f;
#pragma unroll
      for (int j = 0; j < 4; j++) s = fmaf(wa[c * 4 + j], m[j], s);
      ga[c] = fmaxf(s, 0.f);
    }
    float s2 = 0.f;
#pragma unroll
    for (int c = 0; c < 4; c++) s2 = fmaf(wb[o * 4 + c], ga[c], s2);
    g[o] = 1.f / (1.f + expf(-s2));
  }
  for (int idx = threadIdx.x; idx < SRCT * SRCT; idx += 256) {
    int r = idx / SRCT, c = idx % SRCT;
    int hh = h0 + r, ww = w0 + c;
    float v = 0.f;
    if (hh >= 0 && hh < HH && ww >= 0 && ww < WW) v = src[hh * WW + ww];
    tile[r][c] = v;
  }
  __syncthreads();
  for (int idx = threadIdx.x; idx < SRCT * BT; idx += 256) {
    int r = idx / BT, j = idx % BT;
    int cc = j + RAD;
    float s5 = 0.f;
#pragma unroll
    for (int d = -2; d <= 2; d++) s5 += tile[r][cc + d];
    float s15 = s5;
#pragma unroll
    for (int d = 3; d <= 7; d++) s15 += tile[r][cc + d] + tile[r][cc - d];
    float s25 = s15;
#pragma unroll
    for (int d = 8; d <= 12; d++) s25 += tile[r][cc + d] + tile[r][cc - d];
    hs[0][r][j] = s5;
    hs[1][r][j] = s15;
    hs[2][r][j] = s25;
  }
  __syncthreads();
  for (int p = threadIdx.x; p < BT * BT; p += 256) {
    int i = p / BT, j = p % BT;
    int rr = i + RAD;
    float b1 = 0.f;
#pragma unroll
    for (int d = -2; d <= 2; d++) b1 += hs[0][rr + d][j];
    float b2 = 0.f;
#pragma unroll
    for (int d = -7; d <= 7; d++) b2 += hs[1][rr + d][j];
    float b3 = 0.f;
#pragma unroll
    for (int d = -12; d <= 12; d++) b3 += hs[2][rr + d][j];
    b1 *= (1.f / 25.f);
    b2 *= (1.f / 225.f);
    b3 *= (1.f / 625.f);
    float b0 = tile[rr][j + RAD];
    int y = blockIdx.y * BT + i, x = blockIdx.x * BT + j;
    int pix = y * WW + x;
    uint2 pk = *(const uint2*)(pre + (size_t)pix * 16);
    float v[4];
    v[0] = bf2f(pk.x & 0xffffu) * g[0];
    v[1] = bf2f(pk.x >> 16) * g[1];
    v[2] = bf2f(pk.y & 0xffffu) * g[2];
    v[3] = bf2f(pk.y >> 16) * g[3];
    float mx = fmaxf(fmaxf(v[0], v[1]), fmaxf(v[2], v[3]));
    float e0 = expf(v[0] - mx), e1 = expf(v[1] - mx), e2 = expf(v[2] - mx),
          e3 = expf(v[3] - mx);
    float inv = 1.f / (e0 + e1 + e2 + e3);
    dst[pix] = (e0 * b0 + e1 * b1 + e2 * b2 + e3 * b3) * inv;
  }
}

extern "C" void kernel_launch(void* const* d_in, const int* in_sizes, int n_in,
                              void* d_out, int out_size, void* d_ws, size_t ws_size,
                              hipStream_t stream) {
  const float* x = (const float*)d_in[0];
  const float* w1 = (const float*)d_in[1];
  const float* b1 = (const float*)d_in[2];
  const float* a1 = (const float*)d_in[3];
  const float* w2 = (const float*)d_in[4];
  const float* b2 = (const float*)d_in[5];
  const float* a2 = (const float*)d_in[6];
  const float* w3 = (const float*)d_in[7];
  const float* b3 = (const float*)d_in[8];
  const float* a3 = (const float*)d_in[9];
  const float* hw[3] = {(const float*)d_in[10], (const float*)d_in[14], (const float*)d_in[18]};
  const float* hb[3] = {(const float*)d_in[11], (const float*)d_in[15], (const float*)d_in[19]};
  const float* caa[3] = {(const float*)d_in[12], (const float*)d_in[16], (const float*)d_in[20]};
  const float* cab[3] = {(const float*)d_in[13], (const float*)d_in[17], (const float*)d_in[21]};

  char* base = (char*)d_ws;
  size_t off = 0;
  auto alloc = [&](size_t bytes) {
    char* p = base + off;
    off = (off + bytes + 63) & ~(size_t)63;
    return p;
  };
  unsigned short* t1 = (unsigned short*)alloc((size_t)PW * PW * 32 * 2);
  unsigned short* t2 = (unsigned short*)alloc((size_t)PW * PW * 64 * 2);
  unsigned short* pre = (unsigned short*)alloc((size_t)HWSZ * 16 * 2);
  unsigned short* wp2 = (unsigned short*)alloc(9 * 64 * 32 * 2);
  unsigned short* wp3 = (unsigned short*)alloc(9 * 64 * 32 * 2);
  unsigned short* wph = (unsigned short*)alloc(9 * 16 * 32 * 2);
  float* out1 = (float*)alloc((size_t)HWSZ * 4);
  float* out2 = (float*)alloc((size_t)HWSZ * 4);
  float* S = (float*)alloc(8 * 16 * 4);

  dim3 blk(256);
  k_prep<<<932, blk, 0, stream>>>(w2, w3, hw[0], hw[1], hw[2], wp2, wp3, wph, t1, t2, S);

  dim3 gconv(8, 256, 1);    // 64-col blocks x 2-row blocks
  dim3 ghead(4, 256, 1);    // 128-col blocks x 2-row blocks
  dim3 gbc(WW / BT, HH / BT, 1);
  for (int b = 0; b < NB; b++) {
    const float* xb = x + (size_t)b * HWSZ;
    float* Sb = S + b * 16;
    k_conv1<<<HWSZ / 256, blk, 0, stream>>>(xb, w1, b1, a1, t1);
    k_convm<32, 64><<<gconv, blk, 0, stream>>>(t1, wp2, b2, a2, t2);
    k_convm<64, 32><<<gconv, blk, 0, stream>>>(t2, wp3, b3, a3, t1);
    k_headm<<<ghead, blk, 0, stream>>>(t1, wph, hb[0], hb[1], hb[2], pre, Sb);
    float* outb = (float*)d_out + (size_t)b * HWSZ;
    k_blurcombine<<<gbc, blk, 0, stream>>>(xb, pre + 0, Sb + 0, caa[0], cab[0], out1);
    k_blurcombine<<<gbc, blk, 0, stream>>>(out1, pre + 4, Sb + 4, caa[1], cab[1], out2);
    k_blurcombine<<<gbc, blk, 0, stream>>>(out2, pre + 8, Sb + 8, caa[2], cab[2], outb);
  }
}

// Round 5
// 874.165 us; speedup vs baseline: 4.8595x; 1.3678x over previous
//
#include <hip/hip_runtime.h>

#define HH 512
#define WW 512
#define NB 8
#define HWSZ (HH * WW)
#define PW 514  // zero-padded spatial dim for NHWC activation buffers

typedef float f32x4 __attribute__((ext_vector_type(4)));
typedef float f32x16 __attribute__((ext_vector_type(16)));
typedef short bf16x8 __attribute__((ext_vector_type(8)));

__device__ __forceinline__ unsigned short f2bf(float f) {
  union { float f; unsigned u; } v; v.f = f;
  unsigned r = v.u + 0x7FFFu + ((v.u >> 16) & 1u);
  return (unsigned short)(r >> 16);
}
__device__ __forceinline__ float bf2f(unsigned u16) {
  union { unsigned u; float f; } v; v.u = u16 << 16;
  return v.f;
}

// ---- zero the spatial pad ring of a padded NHWC buffer (element i of range) ----
__device__ __forceinline__ void zp(unsigned short* buf, int IC, int i) {
  int rowElems = PW * IC;
  if (i < 2 * rowElems) {  // rows 0 and 513 (full)
    int r = (i < rowElems) ? 0 : (PW - 1);
    int j = i % rowElems;
    buf[(size_t)r * rowElems + j] = 0;
    return;
  }
  i -= 2 * rowElems;
  int r = 1 + i / (2 * IC);
  int j = i % (2 * IC);
  int c = (j < IC) ? 0 : (PW - 1);
  buf[((size_t)r * PW + c) * IC + (j % IC)] = 0;
}

#define PS1 ((size_t)PW * PW * 32)
#define PS2 ((size_t)PW * PW * 64)
#define NZ1 (2 * PW * 32 + 2 * 512 * 32)
#define NZ2 (2 * PW * 64 + 2 * 512 * 64)

// ---- fused one-time prep: weight repacks + pad-ring zero (4 bufs each) + S zero ----
__global__ __launch_bounds__(256) void k_prep(const float* __restrict__ w2,
                                              const float* __restrict__ w3,
                                              const float* __restrict__ h0,
                                              const float* __restrict__ h1,
                                              const float* __restrict__ h2,
                                              unsigned short* __restrict__ wp2,
                                              unsigned short* __restrict__ wp3,
                                              unsigned short* __restrict__ wph,
                                              unsigned short* __restrict__ t1,
                                              unsigned short* __restrict__ t2,
                                              float* __restrict__ S) {
  int i = blockIdx.x * 256 + threadIdx.x;
  const int N1 = 9 * 64 * 32;
  const int N2 = N1 + 9 * 32 * 64;
  const int N3 = N2 + 9 * 16 * 32;
  const int N4 = N3 + 4 * NZ1;
  const int N5 = N4 + 4 * NZ2;
  const int N6 = N5 + 128;
  if (i < N1) {  // w2 [64][32][3][3] -> [9][64][32]
    int ic = i & 31, t = i >> 5, oc = t & 63, k = t >> 6;
    wp2[i] = f2bf(w2[(oc * 32 + ic) * 9 + k]);
  } else if (i < N2) {  // w3 [32][64][3][3] -> [9][32][64]
    int j = i - N1;
    int ic = j & 63, t = j >> 6, oc = t & 31, k = t >> 5;
    wp3[j] = f2bf(w3[(oc * 64 + ic) * 9 + k]);
  } else if (i < N3) {  // heads -> [9][16][32], oc 12..15 zero
    int j = i - N2;
    int ic = j & 31, t = j >> 5, oc = t & 15, k = t >> 4;
    float v = 0.f;
    if (oc < 12) {
      const float* w = oc < 4 ? h0 : (oc < 8 ? h1 : h2);
      v = w[((oc & 3) * 32 + ic) * 9 + k];
    }
    wph[j] = f2bf(v);
  } else if (i < N4) {
    int j = i - N3;
    zp(t1 + (size_t)(j / NZ1) * PS1, 32, j % NZ1);
  } else if (i < N5) {
    int j = i - N4;
    zp(t2 + (size_t)(j / NZ2) * PS2, 64, j % NZ2);
  } else if (i < N6) {
    S[i - N5] = 0.f;
  }
}

// ---- conv1: 1->32, VALU, fp32 in -> padded NHWC bf16 out (z = image in group) ----
__global__ __launch_bounds__(256) void k_conv1(const float* __restrict__ x,
                                               const float* __restrict__ w,
                                               const float* __restrict__ bias,
                                               const float* __restrict__ a_ptr,
                                               unsigned short* __restrict__ out) {
  const float* xp = x + (size_t)blockIdx.z * HWSZ;
  unsigned short* op0 = out + (size_t)blockIdx.z * PS1;
  int pix = blockIdx.x * 256 + threadIdx.x;
  int h = pix >> 9, wc = pix & 511;
  float t[9];
#pragma unroll
  for (int dh = 0; dh < 3; dh++)
#pragma unroll
    for (int dw = 0; dw < 3; dw++) {
      int hh = h + dh - 1, ww = wc + dw - 1;
      t[dh * 3 + dw] =
          (hh >= 0 && hh < HH && ww >= 0 && ww < WW) ? xp[hh * WW + ww] : 0.f;
    }
  float a = a_ptr[0];
  unsigned pk[16];
#pragma unroll
  for (int oc = 0; oc < 32; oc++) {
    float s = bias[oc];
#pragma unroll
    for (int k = 0; k < 9; k++) s = fmaf(w[oc * 9 + k], t[k], s);
    s = s >= 0.f ? s : a * s;
    unsigned short b = f2bf(s);
    if (oc & 1)
      pk[oc >> 1] |= ((unsigned)b) << 16;
    else
      pk[oc >> 1] = b;
  }
  uint4* op = (uint4*)(op0 + ((size_t)(h + 1) * PW + (wc + 1)) * 32);
#pragma unroll
  for (int q = 0; q < 4; q++) op[q] = *(uint4*)&pk[q * 4];
}

// ---- LDS-staged MFMA 3x3 conv (32x32x16), padded NHWC bf16 -> same, bias+prelu ----
// Block: 2 output rows x 64 cols, 4 waves; z = image in group.
template <int IC, int OC>
__global__ __launch_bounds__(256) void k_convm(const unsigned short* __restrict__ in,
                                               const unsigned short* __restrict__ wp,
                                               const float* __restrict__ bias,
                                               const float* __restrict__ a_ptr,
                                               unsigned short* __restrict__ out) {
  constexpr int KS = IC / 16;        // K-steps per tap
  constexpr int MT = OC / 32;        // M tiles
  constexpr int NCH = IC / 8;        // 16B chunks per pixel
  constexpr int LNC = (IC == 32) ? 2 : 3;
  constexpr int SSH = (IC == 32) ? 1 : 0;  // swizzle shift
  constexpr int SMK = NCH - 1;
  constexpr size_t PSIN = (size_t)PW * PW * IC;
  constexpr size_t PSOUT = (size_t)PW * PW * OC;
  __shared__ short lds[4 * 68 * IC];
  const int tid = threadIdx.x;
  const int r0 = blockIdx.y * 2, c0 = blockIdx.x * 64;
  const unsigned short* inz = in + (size_t)blockIdx.z * PSIN;
  unsigned short* outz = out + (size_t)blockIdx.z * PSOUT;

  constexpr int TOT = 4 * 66 * NCH;
  for (int i = tid; i < TOT; i += 256) {
    int ch = i & SMK;
    int p = i >> LNC;
    int prow = p / 66;
    int pcol = p - prow * 66;
    int pl = prow * 68 + pcol;
    uint4 v = *(const uint4*)(inz + ((size_t)(r0 + prow) * PW + (c0 + pcol)) * IC + ch * 8);
    *(uint4*)(&lds[(pl * NCH + (ch ^ ((pl >> SSH) & SMK))) * 8]) = v;
  }
  __syncthreads();

  const int lane = tid & 63, wid = tid >> 6;
  const int l31 = lane & 31, h16 = lane >> 5;
  const int rowsel = wid >> 1, half = wid & 1;

  f32x16 acc[MT];
#pragma unroll
  for (int mt = 0; mt < MT; mt++)
#pragma unroll
    for (int j = 0; j < 16; j++) acc[mt][j] = 0.f;

#pragma unroll
  for (int dh = 0; dh < 3; dh++) {
    bf16x8 af[3][KS][MT];
#pragma unroll
    for (int dw = 0; dw < 3; dw++)
#pragma unroll
      for (int ks = 0; ks < KS; ks++)
#pragma unroll
        for (int mt = 0; mt < MT; mt++)
          af[dw][ks][mt] = *(const bf16x8*)(
              wp + (((dh * 3 + dw) * OC + mt * 32 + l31) * IC + ks * 16 + h16 * 8));
    const int lrow = (rowsel + dh) * 68;
#pragma unroll
    for (int dw = 0; dw < 3; dw++) {
      const int pl = lrow + half * 32 + l31 + dw;
#pragma unroll
      for (int ks = 0; ks < KS; ks++) {
        int blk = (ks * 2 + h16) ^ ((pl >> SSH) & SMK);
        bf16x8 b = *(const bf16x8*)(&lds[(pl * NCH + blk) * 8]);
#pragma unroll
        for (int mt = 0; mt < MT; mt++)
          acc[mt] = __builtin_amdgcn_mfma_f32_32x32x16_bf16(af[dw][ks][mt], b,
                                                            acc[mt], 0, 0, 0);
      }
    }
  }

  const float alpha = a_ptr[0];
  const int orow = r0 + rowsel + 1, ocol = c0 + half * 32 + l31 + 1;
  unsigned short* op = outz + ((size_t)orow * PW + ocol) * OC;
#pragma unroll
  for (int mt = 0; mt < MT; mt++)
#pragma unroll
    for (int g = 0; g < 4; g++) {
      int oc0 = mt * 32 + g * 8 + h16 * 4;
      float v[4];
#pragma unroll
      for (int j = 0; j < 4; j++) {
        float s = acc[mt][g * 4 + j] + bias[oc0 + j];
        v[j] = s >= 0.f ? s : alpha * s;
      }
      uint2 pk;
      pk.x = (unsigned)f2bf(v[0]) | ((unsigned)f2bf(v[1]) << 16);
      pk.y = (unsigned)f2bf(v[2]) | ((unsigned)f2bf(v[3]) << 16);
      *(uint2*)(op + oc0) = pk;
    }
}

// ---- fused 3-head conv 32->16(12 real), LDS-staged 16x16x32; pre + channel sums ----
__global__ __launch_bounds__(256) void k_headm(const unsigned short* __restrict__ in,
                                               const unsigned short* __restrict__ wp,
                                               const float* __restrict__ hb0,
                                               const float* __restrict__ hb1,
                                               const float* __restrict__ hb2,
                                               unsigned short* __restrict__ pre,
                                               float* __restrict__ S) {
  __shared__ short lds[4 * 132 * 32];
  const int tid = threadIdx.x;
  const int r0 = blockIdx.y * 2, c0 = blockIdx.x * 128;
  const unsigned short* inz = in + (size_t)blockIdx.z * PS1;
  unsigned short* prez = pre + (size_t)blockIdx.z * HWSZ * 16;
  float* Sz = S + blockIdx.z * 16;
  for (int i = tid; i < 4 * 130 * 4; i += 256) {
    int ch = i & 3;
    int p = i >> 2;
    int prow = p / 130;
    int pcol = p - prow * 130;
    int pl = prow * 132 + pcol;
    uint4 v = *(const uint4*)(inz + ((size_t)(r0 + prow) * PW + (c0 + pcol)) * 32 + ch * 8);
    *(uint4*)(&lds[(pl * 4 + (ch ^ ((pl >> 1) & 3))) * 8]) = v;
  }
  __syncthreads();

  const int lane = tid & 63, wid = tid >> 6;
  const int l15 = lane & 15, q = lane >> 4;
  const int rowsel = wid >> 1, half = wid & 1;

  f32x4 acc[4];
#pragma unroll
  for (int i = 0; i < 4; i++)
#pragma unroll
    for (int j = 0; j < 4; j++) acc[i][j] = 0.f;

#pragma unroll
  for (int dh = 0; dh < 3; dh++) {
    bf16x8 af[3];
#pragma unroll
    for (int dw = 0; dw < 3; dw++)
      af[dw] = *(const bf16x8*)(wp + ((dh * 3 + dw) * 16 + l15) * 32 + q * 8);
    const int lrow = (rowsel + dh) * 132;
#pragma unroll
    for (int dw = 0; dw < 3; dw++) {
#pragma unroll
      for (int nt = 0; nt < 4; nt++) {
        int pl = lrow + half * 64 + nt * 16 + l15 + dw;
        int blk = q ^ ((pl >> 1) & 3);
        bf16x8 b = *(const bf16x8*)(&lds[(pl * 4 + blk) * 8]);
        acc[nt] = __builtin_amdgcn_mfma_f32_16x16x32_bf16(af[dw], b, acc[nt], 0, 0, 0);
      }
    }
  }

  float bs[4];
#pragma unroll
  for (int r = 0; r < 4; r++) {
    int oc = q * 4 + r;
    bs[r] = oc < 4 ? hb0[oc] : (oc < 8 ? hb1[oc - 4] : (oc < 12 ? hb2[oc - 8] : 0.f));
  }
  float csum[4] = {0.f, 0.f, 0.f, 0.f};
  const int orow = r0 + rowsel;
#pragma unroll
  for (int nt = 0; nt < 4; nt++) {
    int pcol = c0 + half * 64 + nt * 16 + l15;
    int pix = orow * 512 + pcol;
    float v[4];
#pragma unroll
    for (int r = 0; r < 4; r++) {
      v[r] = acc[nt][r] + bs[r];
      csum[r] += v[r];
    }
    uint2 pk;
    pk.x = (unsigned)f2bf(v[0]) | ((unsigned)f2bf(v[1]) << 16);
    pk.y = (unsigned)f2bf(v[2]) | ((unsigned)f2bf(v[3]) << 16);
    *(uint2*)(prez + (size_t)pix * 16 + q * 4) = pk;
  }
#pragma unroll
  for (int d = 1; d < 16; d <<= 1)
#pragma unroll
    for (int r = 0; r < 4; r++) csum[r] += __shfl_xor(csum[r], d, 64);
  __shared__ float part[4][4][4];
  if (l15 == 0)
#pragma unroll
    for (int r = 0; r < 4; r++) part[wid][q][r] = csum[r];
  __syncthreads();
  if (tid < 12) {
    int oc = tid;
    float s = part[0][oc >> 2][oc & 3] + part[1][oc >> 2][oc & 3] +
              part[2][oc >> 2][oc & 3] + part[3][oc >> 2][oc & 3];
    atomicAdd(&Sz[oc], s);
  }
}

// ---- fused: gate + 3 box blurs + softmax(gate*pre) + weighted combine ----
#define BT 32
#define RAD 12
#define SRCT (BT + 2 * RAD)  // 56
__global__ __launch_bounds__(256) void k_blurcombine(const float* __restrict__ src,
                                                     const unsigned short* __restrict__ pre,
                                                     const float* __restrict__ S4,
                                                     const float* __restrict__ wa,
                                                     const float* __restrict__ wb,
                                                     float* __restrict__ dst) {
  __shared__ float tile[SRCT][SRCT];
  __shared__ float hs[3][SRCT][BT];
  __shared__ float g[4];
  const float* srcz = src + (size_t)blockIdx.z * HWSZ;
  const unsigned short* prez = pre + (size_t)blockIdx.z * HWSZ * 16;
  const float* S4z = S4 + blockIdx.z * 16;
  float* dstz = dst + (size_t)blockIdx.z * HWSZ;
  int h0 = blockIdx.y * BT - RAD, w0 = blockIdx.x * BT - RAD;
  if (threadIdx.x < 4) {
    int o = threadIdx.x;
    float m[4], ga[4];
#pragma unroll
    for (int c = 0; c < 4; c++) m[c] = S4z[c] * (1.0f / (float)HWSZ);
#pragma unroll
    for (int c = 0; c < 4; c++) {
      float s = 0.f;
#pragma unroll
      for (int j = 0; j < 4; j++) s = fmaf(wa[c * 4 + j], m[j], s);
      ga[c] = fmaxf(s, 0.f);
    }
    float s2 = 0.f;
#pragma unroll
    for (int c = 0; c < 4; c++) s2 = fmaf(wb[o * 4 + c], ga[c], s2);
    g[o] = 1.f / (1.f + expf(-s2));
  }
  for (int idx = threadIdx.x; idx < SRCT * SRCT; idx += 256) {
    int r = idx / SRCT, c = idx % SRCT;
    int hh = h0 + r, ww = w0 + c;
    float v = 0.f;
    if (hh >= 0 && hh < HH && ww >= 0 && ww < WW) v = srcz[hh * WW + ww];
    tile[r][c] = v;
  }
  __syncthreads();
  for (int idx = threadIdx.x; idx < SRCT * BT; idx += 256) {
    int r = idx / BT, j = idx % BT;
    int cc = j + RAD;
    float s5 = 0.f;
#pragma unroll
    for (int d = -2; d <= 2; d++) s5 += tile[r][cc + d];
    float s15 = s5;
#pragma unroll
    for (int d = 3; d <= 7; d++) s15 += tile[r][cc + d] + tile[r][cc - d];
    float s25 = s15;
#pragma unroll
    for (int d = 8; d <= 12; d++) s25 += tile[r][cc + d] + tile[r][cc - d];
    hs[0][r][j] = s5;
    hs[1][r][j] = s15;
    hs[2][r][j] = s25;
  }
  __syncthreads();
  for (int p = threadIdx.x; p < BT * BT; p += 256) {
    int i = p / BT, j = p % BT;
    int rr = i + RAD;
    float b1 = 0.f;
#pragma unroll
    for (int d = -2; d <= 2; d++) b1 += hs[0][rr + d][j];
    float b2 = 0.f;
#pragma unroll
    for (int d = -7; d <= 7; d++) b2 += hs[1][rr + d][j];
    float b3 = 0.f;
#pragma unroll
    for (int d = -12; d <= 12; d++) b3 += hs[2][rr + d][j];
    b1 *= (1.f / 25.f);
    b2 *= (1.f / 225.f);
    b3 *= (1.f / 625.f);
    float b0 = tile[rr][j + RAD];
    int y = blockIdx.y * BT + i, x = blockIdx.x * BT + j;
    int pix = y * WW + x;
    uint2 pk = *(const uint2*)(prez + (size_t)pix * 16);
    float v[4];
    v[0] = bf2f(pk.x & 0xffffu) * g[0];
    v[1] = bf2f(pk.x >> 16) * g[1];
    v[2] = bf2f(pk.y & 0xffffu) * g[2];
    v[3] = bf2f(pk.y >> 16) * g[3];
    float mx = fmaxf(fmaxf(v[0], v[1]), fmaxf(v[2], v[3]));
    float e0 = expf(v[0] - mx), e1 = expf(v[1] - mx), e2 = expf(v[2] - mx),
          e3 = expf(v[3] - mx);
    float inv = 1.f / (e0 + e1 + e2 + e3);
    dstz[pix] = (e0 * b0 + e1 * b1 + e2 * b2 + e3 * b3) * inv;
  }
}

extern "C" void kernel_launch(void* const* d_in, const int* in_sizes, int n_in,
                              void* d_out, int out_size, void* d_ws, size_t ws_size,
                              hipStream_t stream) {
  const float* x = (const float*)d_in[0];
  const float* w1 = (const float*)d_in[1];
  const float* b1 = (const float*)d_in[2];
  const float* a1 = (const float*)d_in[3];
  const float* w2 = (const float*)d_in[4];
  const float* b2 = (const float*)d_in[5];
  const float* a2 = (const float*)d_in[6];
  const float* w3 = (const float*)d_in[7];
  const float* b3 = (const float*)d_in[8];
  const float* a3 = (const float*)d_in[9];
  const float* hw[3] = {(const float*)d_in[10], (const float*)d_in[14], (const float*)d_in[18]};
  const float* hb[3] = {(const float*)d_in[11], (const float*)d_in[15], (const float*)d_in[19]};
  const float* caa[3] = {(const float*)d_in[12], (const float*)d_in[16], (const float*)d_in[20]};
  const float* cab[3] = {(const float*)d_in[13], (const float*)d_in[17], (const float*)d_in[21]};

  char* base = (char*)d_ws;
  size_t off = 0;
  auto alloc = [&](size_t bytes) {
    char* p = base + off;
    off = (off + bytes + 63) & ~(size_t)63;
    return p;
  };
  // group-of-4 batched buffers: ~234 MiB total (ws is 256 MiB)
  unsigned short* t1 = (unsigned short*)alloc(4 * PS1 * 2);          // 64.5 MiB
  unsigned short* t2 = (unsigned short*)alloc(4 * PS2 * 2);          // 129 MiB
  unsigned short* pre = (unsigned short*)alloc(4 * (size_t)HWSZ * 16 * 2);  // 32 MiB
  unsigned short* wp2 = (unsigned short*)alloc(9 * 64 * 32 * 2);
  unsigned short* wp3 = (unsigned short*)alloc(9 * 64 * 32 * 2);
  unsigned short* wph = (unsigned short*)alloc(9 * 16 * 32 * 2);
  float* out1 = (float*)alloc(4 * (size_t)HWSZ * 4);                 // 4 MiB
  float* out2 = (float*)alloc(4 * (size_t)HWSZ * 4);                 // 4 MiB
  float* S = (float*)alloc(8 * 16 * 4);

  dim3 blk(256);
  {
    int total = 9 * 64 * 32 + 9 * 32 * 64 + 9 * 16 * 32 + 4 * NZ1 + 4 * NZ2 + 128;
    k_prep<<<(total + 255) / 256, blk, 0, stream>>>(w2, w3, hw[0], hw[1], hw[2], wp2,
                                                    wp3, wph, t1, t2, S);
  }

  dim3 gc1(1024, 1, 4);
  dim3 gconv(8, 256, 4);
  dim3 ghead(4, 256, 4);
  dim3 gbc(WW / BT, HH / BT, 4);
  for (int g = 0; g < 2; g++) {
    const float* xg = x + (size_t)g * 4 * HWSZ;
    float* Sg = S + g * 64;
    float* outg = (float*)d_out + (size_t)g * 4 * HWSZ;
    k_conv1<<<gc1, blk, 0, stream>>>(xg, w1, b1, a1, t1);
    k_convm<32, 64><<<gconv, blk, 0, stream>>>(t1, wp2, b2, a2, t2);
    k_convm<64, 32><<<gconv, blk, 0, stream>>>(t2, wp3, b3, a3, t1);
    k_headm<<<ghead, blk, 0, stream>>>(t1, wph, hb[0], hb[1], hb[2], pre, Sg);
    k_blurcombine<<<gbc, blk, 0, stream>>>(xg, pre + 0, Sg + 0, caa[0], cab[0], out1);
    k_blurcombine<<<gbc, blk, 0, stream>>>(out1, pre + 4, Sg + 4, caa[1], cab[1], out2);
    k_blurcombine<<<gbc, blk, 0, stream>>>(out2, pre + 8, Sg + 8, caa[2], cab[2], outg);
  }
}

// Round 6
// 853.483 us; speedup vs baseline: 4.9773x; 1.0242x over previous
//
#include <hip/hip_runtime.h>

#define HH 512
#define WW 512
#define NB 8
#define HWSZ (HH * WW)
#define PW 514  // zero-padded spatial dim for NHWC activation buffers

typedef float f32x4 __attribute__((ext_vector_type(4)));
typedef float f32x16 __attribute__((ext_vector_type(16)));
typedef short bf16x8 __attribute__((ext_vector_type(8)));

__device__ __forceinline__ unsigned short f2bf(float f) {
  union { float f; unsigned u; } v; v.f = f;
  unsigned r = v.u + 0x7FFFu + ((v.u >> 16) & 1u);
  return (unsigned short)(r >> 16);
}
__device__ __forceinline__ float bf2f(unsigned u16) {
  union { unsigned u; float f; } v; v.u = u16 << 16;
  return v.f;
}

// ---- zero the spatial pad ring of a padded NHWC buffer (element i of range) ----
__device__ __forceinline__ void zp(unsigned short* buf, int IC, int i) {
  int rowElems = PW * IC;
  if (i < 2 * rowElems) {  // rows 0 and 513 (full)
    int r = (i < rowElems) ? 0 : (PW - 1);
    int j = i % rowElems;
    buf[(size_t)r * rowElems + j] = 0;
    return;
  }
  i -= 2 * rowElems;
  int r = 1 + i / (2 * IC);
  int j = i % (2 * IC);
  int c = (j < IC) ? 0 : (PW - 1);
  buf[((size_t)r * PW + c) * IC + (j % IC)] = 0;
}

#define PS1 ((size_t)PW * PW * 32)
#define PS2 ((size_t)PW * PW * 64)
#define NZ1 (2 * PW * 32 + 2 * 512 * 32)
#define NZ2 (2 * PW * 64 + 2 * 512 * 64)

// ---- fused one-time prep: weight repacks + pad-ring zero (4 bufs each) + S zero ----
__global__ __launch_bounds__(256) void k_prep(const float* __restrict__ w2,
                                              const float* __restrict__ w3,
                                              const float* __restrict__ h0,
                                              const float* __restrict__ h1,
                                              const float* __restrict__ h2,
                                              unsigned short* __restrict__ wp2,
                                              unsigned short* __restrict__ wp3,
                                              unsigned short* __restrict__ wph,
                                              unsigned short* __restrict__ t1,
                                              unsigned short* __restrict__ t2,
                                              float* __restrict__ S) {
  int i = blockIdx.x * 256 + threadIdx.x;
  const int N1 = 9 * 64 * 32;
  const int N2 = N1 + 9 * 32 * 64;
  const int N3 = N2 + 9 * 16 * 32;
  const int N4 = N3 + 4 * NZ1;
  const int N5 = N4 + 4 * NZ2;
  const int N6 = N5 + 128;
  if (i < N1) {  // w2 [64][32][3][3] -> [9][64][32]
    int ic = i & 31, t = i >> 5, oc = t & 63, k = t >> 6;
    wp2[i] = f2bf(w2[(oc * 32 + ic) * 9 + k]);
  } else if (i < N2) {  // w3 [32][64][3][3] -> [9][32][64]
    int j = i - N1;
    int ic = j & 63, t = j >> 6, oc = t & 31, k = t >> 5;
    wp3[j] = f2bf(w3[(oc * 64 + ic) * 9 + k]);
  } else if (i < N3) {  // heads -> [9][16][32], oc 12..15 zero
    int j = i - N2;
    int ic = j & 31, t = j >> 5, oc = t & 15, k = t >> 4;
    float v = 0.f;
    if (oc < 12) {
      const float* w = oc < 4 ? h0 : (oc < 8 ? h1 : h2);
      v = w[((oc & 3) * 32 + ic) * 9 + k];
    }
    wph[j] = f2bf(v);
  } else if (i < N4) {
    int j = i - N3;
    zp(t1 + (size_t)(j / NZ1) * PS1, 32, j % NZ1);
  } else if (i < N5) {
    int j = i - N4;
    zp(t2 + (size_t)(j / NZ2) * PS2, 64, j % NZ2);
  } else if (i < N6) {
    S[i - N5] = 0.f;
  }
}

// ---- conv1: 1->32, VALU, fp32 in -> padded NHWC bf16 out (z = image in group) ----
__global__ __launch_bounds__(256) void k_conv1(const float* __restrict__ x,
                                               const float* __restrict__ w,
                                               const float* __restrict__ bias,
                                               const float* __restrict__ a_ptr,
                                               unsigned short* __restrict__ out) {
  const float* xp = x + (size_t)blockIdx.z * HWSZ;
  unsigned short* op0 = out + (size_t)blockIdx.z * PS1;
  int pix = blockIdx.x * 256 + threadIdx.x;
  int h = pix >> 9, wc = pix & 511;
  float t[9];
#pragma unroll
  for (int dh = 0; dh < 3; dh++)
#pragma unroll
    for (int dw = 0; dw < 3; dw++) {
      int hh = h + dh - 1, ww = wc + dw - 1;
      t[dh * 3 + dw] =
          (hh >= 0 && hh < HH && ww >= 0 && ww < WW) ? xp[hh * WW + ww] : 0.f;
    }
  float a = a_ptr[0];
  unsigned pk[16];
#pragma unroll
  for (int oc = 0; oc < 32; oc++) {
    float s = bias[oc];
#pragma unroll
    for (int k = 0; k < 9; k++) s = fmaf(w[oc * 9 + k], t[k], s);
    s = s >= 0.f ? s : a * s;
    unsigned short b = f2bf(s);
    if (oc & 1)
      pk[oc >> 1] |= ((unsigned)b) << 16;
    else
      pk[oc >> 1] = b;
  }
  uint4* op = (uint4*)(op0 + ((size_t)(h + 1) * PW + (wc + 1)) * 32);
#pragma unroll
  for (int q = 0; q < 4; q++) op[q] = *(uint4*)&pk[q * 4];
}

// ---- LDS-staged MFMA 3x3 conv (32x32x16): 4 rows x 64 cols per block ----
// Wave = 1 output row, 2 independent 32-px N-tiles (ILP). A-frags per (dh,dw).
template <int IC, int OC>
__global__ __launch_bounds__(256) void k_convm(const unsigned short* __restrict__ in,
                                               const unsigned short* __restrict__ wp,
                                               const float* __restrict__ bias,
                                               const float* __restrict__ a_ptr,
                                               unsigned short* __restrict__ out) {
  constexpr int KS = IC / 16;        // K-steps per tap
  constexpr int MT = OC / 32;        // M tiles
  constexpr int NCH = IC / 8;        // 16B chunks per pixel
  constexpr int LNC = (IC == 32) ? 2 : 3;
  constexpr int SSH = (IC == 32) ? 1 : 0;  // swizzle shift
  constexpr int SMK = NCH - 1;
  constexpr size_t PSIN = (size_t)PW * PW * IC;
  constexpr size_t PSOUT = (size_t)PW * PW * OC;
  __shared__ short lds[6 * 68 * IC];
  const int tid = threadIdx.x;
  const int r0 = blockIdx.y * 4, c0 = blockIdx.x * 64;
  const unsigned short* inz = in + (size_t)blockIdx.z * PSIN;
  unsigned short* outz = out + (size_t)blockIdx.z * PSOUT;

  // stage 6 rows x 66 cols (halo for 4 output rows), swizzled 16B chunks
  constexpr int TOT = 6 * 66 * NCH;
  for (int i = tid; i < TOT; i += 256) {
    int ch = i & SMK;
    int p = i >> LNC;
    int prow = p / 66;
    int pcol = p - prow * 66;
    int pl = prow * 68 + pcol;
    uint4 v = *(const uint4*)(inz + ((size_t)(r0 + prow) * PW + (c0 + pcol)) * IC + ch * 8);
    *(uint4*)(&lds[(pl * NCH + (ch ^ ((pl >> SSH) & SMK))) * 8]) = v;
  }
  __syncthreads();

  const int lane = tid & 63, wid = tid >> 6;
  const int l31 = lane & 31, h16 = lane >> 5;

  f32x16 acc[2][MT];
#pragma unroll
  for (int nt = 0; nt < 2; nt++)
#pragma unroll
    for (int mt = 0; mt < MT; mt++)
#pragma unroll
      for (int j = 0; j < 16; j++) acc[nt][mt][j] = 0.f;

#pragma unroll
  for (int dh = 0; dh < 3; dh++) {
    const int lrow = (wid + dh) * 68;
#pragma unroll
    for (int dw = 0; dw < 3; dw++) {
      bf16x8 af[KS][MT];
#pragma unroll
      for (int ks = 0; ks < KS; ks++)
#pragma unroll
        for (int mt = 0; mt < MT; mt++)
          af[ks][mt] = *(const bf16x8*)(
              wp + (((dh * 3 + dw) * OC + mt * 32 + l31) * IC + ks * 16 + h16 * 8));
      const int plb = lrow + l31 + dw;
#pragma unroll
      for (int ks = 0; ks < KS; ks++) {
        int pl0 = plb;
        int pl1 = plb + 32;
        int blk0 = (ks * 2 + h16) ^ ((pl0 >> SSH) & SMK);
        int blk1 = (ks * 2 + h16) ^ ((pl1 >> SSH) & SMK);
        bf16x8 b0 = *(const bf16x8*)(&lds[(pl0 * NCH + blk0) * 8]);
        bf16x8 b1 = *(const bf16x8*)(&lds[(pl1 * NCH + blk1) * 8]);
#pragma unroll
        for (int mt = 0; mt < MT; mt++)
          acc[0][mt] = __builtin_amdgcn_mfma_f32_32x32x16_bf16(af[ks][mt], b0,
                                                               acc[0][mt], 0, 0, 0);
#pragma unroll
        for (int mt = 0; mt < MT; mt++)
          acc[1][mt] = __builtin_amdgcn_mfma_f32_32x32x16_bf16(af[ks][mt], b1,
                                                               acc[1][mt], 0, 0, 0);
      }
    }
  }

  const float alpha = a_ptr[0];
  const int orow = r0 + wid + 1;
#pragma unroll
  for (int nt = 0; nt < 2; nt++) {
    const int ocol = c0 + nt * 32 + l31 + 1;
    unsigned short* op = outz + ((size_t)orow * PW + ocol) * OC;
#pragma unroll
    for (int mt = 0; mt < MT; mt++)
#pragma unroll
      for (int g = 0; g < 4; g++) {
        int oc0 = mt * 32 + g * 8 + h16 * 4;
        float v[4];
#pragma unroll
        for (int j = 0; j < 4; j++) {
          float s = acc[nt][mt][g * 4 + j] + bias[oc0 + j];
          v[j] = s >= 0.f ? s : alpha * s;
        }
        uint2 pk;
        pk.x = (unsigned)f2bf(v[0]) | ((unsigned)f2bf(v[1]) << 16);
        pk.y = (unsigned)f2bf(v[2]) | ((unsigned)f2bf(v[3]) << 16);
        *(uint2*)(op + oc0) = pk;
      }
  }
}

// ---- fused 3-head conv 32->16(12 real), LDS-staged 16x16x32; pre + channel sums ----
__global__ __launch_bounds__(256) void k_headm(const unsigned short* __restrict__ in,
                                               const unsigned short* __restrict__ wp,
                                               const float* __restrict__ hb0,
                                               const float* __restrict__ hb1,
                                               const float* __restrict__ hb2,
                                               unsigned short* __restrict__ pre,
                                               float* __restrict__ S) {
  __shared__ short lds[4 * 132 * 32];
  const int tid = threadIdx.x;
  const int r0 = blockIdx.y * 2, c0 = blockIdx.x * 128;
  const unsigned short* inz = in + (size_t)blockIdx.z * PS1;
  unsigned short* prez = pre + (size_t)blockIdx.z * HWSZ * 16;
  float* Sz = S + blockIdx.z * 16;
  for (int i = tid; i < 4 * 130 * 4; i += 256) {
    int ch = i & 3;
    int p = i >> 2;
    int prow = p / 130;
    int pcol = p - prow * 130;
    int pl = prow * 132 + pcol;
    uint4 v = *(const uint4*)(inz + ((size_t)(r0 + prow) * PW + (c0 + pcol)) * 32 + ch * 8);
    *(uint4*)(&lds[(pl * 4 + (ch ^ ((pl >> 1) & 3))) * 8]) = v;
  }
  __syncthreads();

  const int lane = tid & 63, wid = tid >> 6;
  const int l15 = lane & 15, q = lane >> 4;
  const int rowsel = wid >> 1, half = wid & 1;

  f32x4 acc[4];
#pragma unroll
  for (int i = 0; i < 4; i++)
#pragma unroll
    for (int j = 0; j < 4; j++) acc[i][j] = 0.f;

#pragma unroll
  for (int dh = 0; dh < 3; dh++) {
    bf16x8 af[3];
#pragma unroll
    for (int dw = 0; dw < 3; dw++)
      af[dw] = *(const bf16x8*)(wp + ((dh * 3 + dw) * 16 + l15) * 32 + q * 8);
    const int lrow = (rowsel + dh) * 132;
#pragma unroll
    for (int dw = 0; dw < 3; dw++) {
#pragma unroll
      for (int nt = 0; nt < 4; nt++) {
        int pl = lrow + half * 64 + nt * 16 + l15 + dw;
        int blk = q ^ ((pl >> 1) & 3);
        bf16x8 b = *(const bf16x8*)(&lds[(pl * 4 + blk) * 8]);
        acc[nt] = __builtin_amdgcn_mfma_f32_16x16x32_bf16(af[dw], b, acc[nt], 0, 0, 0);
      }
    }
  }

  float bs[4];
#pragma unroll
  for (int r = 0; r < 4; r++) {
    int oc = q * 4 + r;
    bs[r] = oc < 4 ? hb0[oc] : (oc < 8 ? hb1[oc - 4] : (oc < 12 ? hb2[oc - 8] : 0.f));
  }
  float csum[4] = {0.f, 0.f, 0.f, 0.f};
  const int orow = r0 + rowsel;
#pragma unroll
  for (int nt = 0; nt < 4; nt++) {
    int pcol = c0 + half * 64 + nt * 16 + l15;
    int pix = orow * 512 + pcol;
    float v[4];
#pragma unroll
    for (int r = 0; r < 4; r++) {
      v[r] = acc[nt][r] + bs[r];
      csum[r] += v[r];
    }
    uint2 pk;
    pk.x = (unsigned)f2bf(v[0]) | ((unsigned)f2bf(v[1]) << 16);
    pk.y = (unsigned)f2bf(v[2]) | ((unsigned)f2bf(v[3]) << 16);
    *(uint2*)(prez + (size_t)pix * 16 + q * 4) = pk;
  }
#pragma unroll
  for (int d = 1; d < 16; d <<= 1)
#pragma unroll
    for (int r = 0; r < 4; r++) csum[r] += __shfl_xor(csum[r], d, 64);
  __shared__ float part[4][4][4];
  if (l15 == 0)
#pragma unroll
    for (int r = 0; r < 4; r++) part[wid][q][r] = csum[r];
  __syncthreads();
  if (tid < 12) {
    int oc = tid;
    float s = part[0][oc >> 2][oc & 3] + part[1][oc >> 2][oc & 3] +
              part[2][oc >> 2][oc & 3] + part[3][oc >> 2][oc & 3];
    atomicAdd(&Sz[oc], s);
  }
}

// ---- fused: gate + 3 box blurs + softmax(gate*pre) + weighted combine ----
#define BT 32
#define RAD 12
#define SRCT (BT + 2 * RAD)  // 56
__global__ __launch_bounds__(256) void k_blurcombine(const float* __restrict__ src,
                                                     const unsigned short* __restrict__ pre,
                                                     const float* __restrict__ S4,
                                                     const float* __restrict__ wa,
                                                     const float* __restrict__ wb,
                                                     float* __restrict__ dst) {
  __shared__ float tile[SRCT][SRCT];
  __shared__ float hs[3][SRCT][BT];
  __shared__ float g[4];
  const float* srcz = src + (size_t)blockIdx.z * HWSZ;
  const unsigned short* prez = pre + (size_t)blockIdx.z * HWSZ * 16;
  const float* S4z = S4 + blockIdx.z * 16;
  float* dstz = dst + (size_t)blockIdx.z * HWSZ;
  int h0 = blockIdx.y * BT - RAD, w0 = blockIdx.x * BT - RAD;
  if (threadIdx.x < 4) {
    int o = threadIdx.x;
    float m[4], ga[4];
#pragma unroll
    for (int c = 0; c < 4; c++) m[c] = S4z[c] * (1.0f / (float)HWSZ);
#pragma unroll
    for (int c = 0; c < 4; c++) {
      float s = 0.f;
#pragma unroll
      for (int j = 0; j < 4; j++) s = fmaf(wa[c * 4 + j], m[j], s);
      ga[c] = fmaxf(s, 0.f);
    }
    float s2 = 0.f;
#pragma unroll
    for (int c = 0; c < 4; c++) s2 = fmaf(wb[o * 4 + c], ga[c], s2);
    g[o] = 1.f / (1.f + expf(-s2));
  }
  for (int idx = threadIdx.x; idx < SRCT * SRCT; idx += 256) {
    int r = idx / SRCT, c = idx % SRCT;
    int hh = h0 + r, ww = w0 + c;
    float v = 0.f;
    if (hh >= 0 && hh < HH && ww >= 0 && ww < WW) v = srcz[hh * WW + ww];
    tile[r][c] = v;
  }
  __syncthreads();
  for (int idx = threadIdx.x; idx < SRCT * BT; idx += 256) {
    int r = idx / BT, j = idx % BT;
    int cc = j + RAD;
    float s5 = 0.f;
#pragma unroll
    for (int d = -2; d <= 2; d++) s5 += tile[r][cc + d];
    float s15 = s5;
#pragma unroll
    for (int d = 3; d <= 7; d++) s15 += tile[r][cc + d] + tile[r][cc - d];
    float s25 = s15;
#pragma unroll
    for (int d = 8; d <= 12; d++) s25 += tile[r][cc + d] + tile[r][cc - d];
    hs[0][r][j] = s5;
    hs[1][r][j] = s15;
    hs[2][r][j] = s25;
  }
  __syncthreads();
  for (int p = threadIdx.x; p < BT * BT; p += 256) {
    int i = p / BT, j = p % BT;
    int rr = i + RAD;
    float b1 = 0.f;
#pragma unroll
    for (int d = -2; d <= 2; d++) b1 += hs[0][rr + d][j];
    float b2 = 0.f;
#pragma unroll
    for (int d = -7; d <= 7; d++) b2 += hs[1][rr + d][j];
    float b3 = 0.f;
#pragma unroll
    for (int d = -12; d <= 12; d++) b3 += hs[2][rr + d][j];
    b1 *= (1.f / 25.f);
    b2 *= (1.f / 225.f);
    b3 *= (1.f / 625.f);
    float b0 = tile[rr][j + RAD];
    int y = blockIdx.y * BT + i, x = blockIdx.x * BT + j;
    int pix = y * WW + x;
    uint2 pk = *(const uint2*)(prez + (size_t)pix * 16);
    float v[4];
    v[0] = bf2f(pk.x & 0xffffu) * g[0];
    v[1] = bf2f(pk.x >> 16) * g[1];
    v[2] = bf2f(pk.y & 0xffffu) * g[2];
    v[3] = bf2f(pk.y >> 16) * g[3];
    float mx = fmaxf(fmaxf(v[0], v[1]), fmaxf(v[2], v[3]));
    float e0 = expf(v[0] - mx), e1 = expf(v[1] - mx), e2 = expf(v[2] - mx),
          e3 = expf(v[3] - mx);
    float inv = 1.f / (e0 + e1 + e2 + e3);
    dstz[pix] = (e0 * b0 + e1 * b1 + e2 * b2 + e3 * b3) * inv;
  }
}

extern "C" void kernel_launch(void* const* d_in, const int* in_sizes, int n_in,
                              void* d_out, int out_size, void* d_ws, size_t ws_size,
                              hipStream_t stream) {
  const float* x = (const float*)d_in[0];
  const float* w1 = (const float*)d_in[1];
  const float* b1 = (const float*)d_in[2];
  const float* a1 = (const float*)d_in[3];
  const float* w2 = (const float*)d_in[4];
  const float* b2 = (const float*)d_in[5];
  const float* a2 = (const float*)d_in[6];
  const float* w3 = (const float*)d_in[7];
  const float* b3 = (const float*)d_in[8];
  const float* a3 = (const float*)d_in[9];
  const float* hw[3] = {(const float*)d_in[10], (const float*)d_in[14], (const float*)d_in[18]};
  const float* hb[3] = {(const float*)d_in[11], (const float*)d_in[15], (const float*)d_in[19]};
  const float* caa[3] = {(const float*)d_in[12], (const float*)d_in[16], (const float*)d_in[20]};
  const float* cab[3] = {(const float*)d_in[13], (const float*)d_in[17], (const float*)d_in[21]};

  char* base = (char*)d_ws;
  size_t off = 0;
  auto alloc = [&](size_t bytes) {
    char* p = base + off;
    off = (off + bytes + 63) & ~(size_t)63;
    return p;
  };
  // group-of-4 batched buffers: ~234 MiB total (ws is 256 MiB)
  unsigned short* t1 = (unsigned short*)alloc(4 * PS1 * 2);          // 64.5 MiB
  unsigned short* t2 = (unsigned short*)alloc(4 * PS2 * 2);          // 129 MiB
  unsigned short* pre = (unsigned short*)alloc(4 * (size_t)HWSZ * 16 * 2);  // 32 MiB
  unsigned short* wp2 = (unsigned short*)alloc(9 * 64 * 32 * 2);
  unsigned short* wp3 = (unsigned short*)alloc(9 * 64 * 32 * 2);
  unsigned short* wph = (unsigned short*)alloc(9 * 16 * 32 * 2);
  float* out1 = (float*)alloc(4 * (size_t)HWSZ * 4);                 // 4 MiB
  float* out2 = (float*)alloc(4 * (size_t)HWSZ * 4);                 // 4 MiB
  float* S = (float*)alloc(8 * 16 * 4);

  dim3 blk(256);
  {
    int total = 9 * 64 * 32 + 9 * 32 * 64 + 9 * 16 * 32 + 4 * NZ1 + 4 * NZ2 + 128;
    k_prep<<<(total + 255) / 256, blk, 0, stream>>>(w2, w3, hw[0], hw[1], hw[2], wp2,
                                                    wp3, wph, t1, t2, S);
  }

  dim3 gc1(1024, 1, 4);
  dim3 gconv(8, 128, 4);    // 64-col x 4-row blocks
  dim3 ghead(4, 256, 4);
  dim3 gbc(WW / BT, HH / BT, 4);
  for (int g = 0; g < 2; g++) {
    const float* xg = x + (size_t)g * 4 * HWSZ;
    float* Sg = S + g * 64;
    float* outg = (float*)d_out + (size_t)g * 4 * HWSZ;
    k_conv1<<<gc1, blk, 0, stream>>>(xg, w1, b1, a1, t1);
    k_convm<32, 64><<<gconv, blk, 0, stream>>>(t1, wp2, b2, a2, t2);
    k_convm<64, 32><<<gconv, blk, 0, stream>>>(t2, wp3, b3, a3, t1);
    k_headm<<<ghead, blk, 0, stream>>>(t1, wph, hb[0], hb[1], hb[2], pre, Sg);
    k_blurcombine<<<gbc, blk, 0, stream>>>(xg, pre + 0, Sg + 0, caa[0], cab[0], out1);
    k_blurcombine<<<gbc, blk, 0, stream>>>(out1, pre + 4, Sg + 4, caa[1], cab[1], out2);
    k_blurcombine<<<gbc, blk, 0, stream>>>(out2, pre + 8, Sg + 8, caa[2], cab[2], outg);
  }
}

// Round 7
// 590.338 us; speedup vs baseline: 7.1959x; 1.4458x over previous
//
#include <hip/hip_runtime.h>

#define HH 512
#define WW 512
#define NB 8
#define HWSZ (HH * WW)
#define PW 516   // padded row stride (cols 0..515; image at 1..512; col 513 zero; 514/515 junk)
#define PROWS 514  // rows 0..513; image rows at 1..512

typedef float f32x4 __attribute__((ext_vector_type(4)));
typedef float f32x16 __attribute__((ext_vector_type(16)));
typedef short bf16x8 __attribute__((ext_vector_type(8)));

__device__ __forceinline__ unsigned short f2bf(float f) {
  union { float f; unsigned u; } v; v.f = f;
  unsigned r = v.u + 0x7FFFu + ((v.u >> 16) & 1u);
  return (unsigned short)(r >> 16);
}
__device__ __forceinline__ float bf2f(unsigned u16) {
  union { unsigned u; float f; } v; v.u = u16 << 16;
  return v.f;
}

// async global->LDS copy, 16B per lane; l must be wave-uniform, dest = l + lane*16
__device__ __forceinline__ void gload16(const uint4* g, uint4* l) {
  __builtin_amdgcn_global_load_lds((__attribute__((address_space(1))) void*)g,
                                   (__attribute__((address_space(3))) void*)l, 16, 0, 0);
}

// shorts per padded image plane (chunk-major: [row][chunk][col] 16B chunks)
#define PS1 ((size_t)PROWS * PW * 32)
#define PS2 ((size_t)PROWS * PW * 64)
// zero-ring element counts (shorts) per buffer
#define NZ1 (2 * 4 * PW * 8 + 512 * 4 * 16)
#define NZ2 (2 * 8 * PW * 8 + 512 * 8 * 16)

// ---- zero pad ring, chunk-major layout; i indexes the elements to zero ----
__device__ __forceinline__ void zp(unsigned short* buf, int NCH, int i) {
  int rowShorts = NCH * PW * 8;
  if (i < 2 * rowShorts) {  // rows 0 and 513, full width
    size_t r = (i < rowShorts) ? 0 : 513;
    int j = i % rowShorts;
    buf[r * rowShorts + j] = 0;
    return;
  }
  i -= 2 * rowShorts;
  int perRow = NCH * 16;  // 2 cols x 8 shorts per chunk
  int r = 1 + i / perRow;
  int j = i % perRow;
  int ch = j >> 4;
  int c = (j & 8) ? 513 : 0;
  int e = j & 7;
  buf[(((size_t)r * NCH + ch) * PW + c) * 8 + e] = 0;
}

// ---- fused one-time prep: weight repacks + pad-ring zero (4 bufs each) + S zero ----
__global__ __launch_bounds__(256) void k_prep(const float* __restrict__ w2,
                                              const float* __restrict__ w3,
                                              const float* __restrict__ h0,
                                              const float* __restrict__ h1,
                                              const float* __restrict__ h2,
                                              unsigned short* __restrict__ wp2,
                                              unsigned short* __restrict__ wp3,
                                              unsigned short* __restrict__ wph,
                                              unsigned short* __restrict__ t1,
                                              unsigned short* __restrict__ t2,
                                              float* __restrict__ S) {
  int i = blockIdx.x * 256 + threadIdx.x;
  const int N1 = 9 * 64 * 32;
  const int N2 = N1 + 9 * 32 * 64;
  const int N3 = N2 + 9 * 16 * 32;
  const int N4 = N3 + 4 * NZ1;
  const int N5 = N4 + 4 * NZ2;
  const int N6 = N5 + 128;
  if (i < N1) {  // w2 [64][32][3][3] -> [9][64][32]
    int ic = i & 31, t = i >> 5, oc = t & 63, k = t >> 6;
    wp2[i] = f2bf(w2[(oc * 32 + ic) * 9 + k]);
  } else if (i < N2) {  // w3 [32][64][3][3] -> [9][32][64]
    int j = i - N1;
    int ic = j & 63, t = j >> 6, oc = t & 31, k = t >> 5;
    wp3[j] = f2bf(w3[(oc * 64 + ic) * 9 + k]);
  } else if (i < N3) {  // heads -> [9][16][32], oc 12..15 zero
    int j = i - N2;
    int ic = j & 31, t = j >> 5, oc = t & 15, k = t >> 4;
    float v = 0.f;
    if (oc < 12) {
      const float* w = oc < 4 ? h0 : (oc < 8 ? h1 : h2);
      v = w[((oc & 3) * 32 + ic) * 9 + k];
    }
    wph[j] = f2bf(v);
  } else if (i < N4) {
    int j = i - N3;
    zp(t1 + (size_t)(j / NZ1) * PS1, 4, j % NZ1);
  } else if (i < N5) {
    int j = i - N4;
    zp(t2 + (size_t)(j / NZ2) * PS2, 8, j % NZ2);
  } else if (i < N6) {
    S[i - N5] = 0.f;
  }
}

// ---- conv1: 1->32, VALU, fp32 in -> padded chunk-major bf16 out ----
__global__ __launch_bounds__(256) void k_conv1(const float* __restrict__ x,
                                               const float* __restrict__ w,
                                               const float* __restrict__ bias,
                                               const float* __restrict__ a_ptr,
                                               unsigned short* __restrict__ out) {
  const float* xp = x + (size_t)blockIdx.z * HWSZ;
  uint4* out4 = (uint4*)(out + (size_t)blockIdx.z * PS1);
  int pix = blockIdx.x * 256 + threadIdx.x;
  int h = pix >> 9, wc = pix & 511;
  float t[9];
#pragma unroll
  for (int dh = 0; dh < 3; dh++)
#pragma unroll
    for (int dw = 0; dw < 3; dw++) {
      int hh = h + dh - 1, ww = wc + dw - 1;
      t[dh * 3 + dw] =
          (hh >= 0 && hh < HH && ww >= 0 && ww < WW) ? xp[hh * WW + ww] : 0.f;
    }
  float a = a_ptr[0];
  unsigned pk[16];
#pragma unroll
  for (int oc = 0; oc < 32; oc++) {
    float s = bias[oc];
#pragma unroll
    for (int k = 0; k < 9; k++) s = fmaf(w[oc * 9 + k], t[k], s);
    s = s >= 0.f ? s : a * s;
    unsigned short b = f2bf(s);
    if (oc & 1)
      pk[oc >> 1] |= ((unsigned)b) << 16;
    else
      pk[oc >> 1] = b;
  }
#pragma unroll
  for (int q = 0; q < 4; q++)
    out4[((size_t)(h + 1) * 4 + q) * PW + (wc + 1)] = *(uint4*)&pk[q * 4];
}

// ---- strip-marching MFMA 3x3 conv (32x32x16), chunk-major, global_load_lds staging ----
// Block: 64 cols x 32 rows (8 iters of 4 rows), 8-slot LDS row ring, A-frags in VGPR.
template <int IC, int OC>
__global__ __launch_bounds__(256, 2) void k_convm(const unsigned short* __restrict__ in,
                                                  const unsigned short* __restrict__ wp,
                                                  const float* __restrict__ bias,
                                                  const float* __restrict__ a_ptr,
                                                  unsigned short* __restrict__ out) {
  constexpr int KS = IC / 16;   // K-steps per tap
  constexpr int MT = OC / 32;   // M tiles
  constexpr int NCH = IC / 8;   // 16B chunks per pixel
  constexpr int NCHO = OC / 8;
  constexpr size_t PSIN = (size_t)PROWS * PW * IC;
  constexpr size_t PSOUT = (size_t)PROWS * PW * OC;
  __shared__ __align__(16) short lds[8 * NCH * 68 * 8];  // [slot][ch][px(68)] 16B chunks
  const int tid = threadIdx.x, lane = tid & 63, wid = tid >> 6;
  const int l31 = lane & 31, h16 = lane >> 5;
  const int c0 = blockIdx.x * 64;
  const int R0 = blockIdx.y * 32;
  const uint4* in4 = (const uint4*)(in + (size_t)blockIdx.z * PSIN);
  unsigned short* outz = out + (size_t)blockIdx.z * PSOUT;
  uint4* lds4 = (uint4*)lds;

  // A-fragments: all 9 taps, register-resident for the whole block
  bf16x8 af[9][KS][MT];
#pragma unroll
  for (int k9 = 0; k9 < 9; k9++)
#pragma unroll
    for (int ks = 0; ks < KS; ks++)
#pragma unroll
      for (int mt = 0; mt < MT; mt++)
        af[k9][ks][mt] = *(const bf16x8*)(
            wp + ((size_t)(k9 * OC + mt * 32 + l31) * IC + ks * 16 + h16 * 8));

  auto load_rows = [&](int rfirst, int nrows) {
    int nseg = nrows * NCH;
    for (int sg = wid; sg < nseg; sg += 4) {
      int rr = rfirst + sg / NCH;
      int ch = sg - (sg / NCH) * NCH;
      const uint4* src = in4 + (size_t)(rr * NCH + ch) * PW + c0;
      uint4* dst = lds4 + ((rr & 7) * NCH + ch) * 68;
      gload16(src + lane, dst);        // px 0..63
      gload16(src + 4 + lane, dst + 4); // px 4..67 (overlap rewrite, same data)
    }
  };

  const float alpha = a_ptr[0];
  load_rows(R0, 6);

  for (int k = 0; k < 8; ++k) {
    const int rb = R0 + 4 * k;
    __syncthreads();                 // drains pending loads (rows rb..rb+5 ready)
    if (k < 7) load_rows(rb + 6, 2); // prefetch, overlaps compute (slots rb+6,rb+7 free)

    f32x16 acc[2][MT];
#pragma unroll
    for (int nt = 0; nt < 2; nt++)
#pragma unroll
      for (int mt = 0; mt < MT; mt++)
#pragma unroll
        for (int j = 0; j < 16; j++) acc[nt][mt][j] = 0.f;

#pragma unroll
    for (int dh = 0; dh < 3; dh++) {
      const short* lrow = lds + (size_t)((rb + wid + dh) & 7) * NCH * 68 * 8;
#pragma unroll
      for (int dw = 0; dw < 3; dw++) {
        const int pl0 = l31 + dw, pl1 = 32 + l31 + dw;
#pragma unroll
        for (int ks = 0; ks < KS; ks++) {
          const int blk = ks * 2 + h16;
          bf16x8 b0 = *(const bf16x8*)(lrow + (blk * 68 + pl0) * 8);
          bf16x8 b1 = *(const bf16x8*)(lrow + (blk * 68 + pl1) * 8);
#pragma unroll
          for (int mt = 0; mt < MT; mt++)
            acc[0][mt] = __builtin_amdgcn_mfma_f32_32x32x16_bf16(af[dh * 3 + dw][ks][mt],
                                                                 b0, acc[0][mt], 0, 0, 0);
#pragma unroll
          for (int mt = 0; mt < MT; mt++)
            acc[1][mt] = __builtin_amdgcn_mfma_f32_32x32x16_bf16(af[dh * 3 + dw][ks][mt],
                                                                 b1, acc[1][mt], 0, 0, 0);
        }
      }
    }

    // epilogue: coalesced chunk-major stores (512B contiguous per instruction)
    const int orow = rb + wid + 1;
    uint2* o2 = (uint2*)outz;
#pragma unroll
    for (int nt = 0; nt < 2; nt++) {
      const int ocol = c0 + nt * 32 + l31 + 1;
#pragma unroll
      for (int mt = 0; mt < MT; mt++)
#pragma unroll
        for (int g = 0; g < 4; g++) {
          int oc0 = mt * 32 + g * 8 + h16 * 4;
          f32x4 bv = *(const f32x4*)(bias + oc0);
          float v[4];
#pragma unroll
          for (int j = 0; j < 4; j++) {
            float s = acc[nt][mt][g * 4 + j] + bv[j];
            v[j] = s >= 0.f ? s : alpha * s;
          }
          uint2 pk;
          pk.x = (unsigned)f2bf(v[0]) | ((unsigned)f2bf(v[1]) << 16);
          pk.y = (unsigned)f2bf(v[2]) | ((unsigned)f2bf(v[3]) << 16);
          size_t idx16 = ((size_t)orow * NCHO + (mt * 4 + g)) * PW + ocol;
          o2[idx16 * 2 + h16] = pk;
        }
    }
    __syncthreads();                 // all waves done reading slots rb, rb+1
    if (k < 7) load_rows(rb + 8, 2); // into freed slots; drained at next iter's sync
  }
}

// ---- fused 3-head conv 32->16(12 real), LDS-staged 16x16x32; pre + channel sums ----
__global__ __launch_bounds__(256) void k_headm(const unsigned short* __restrict__ in,
                                               const unsigned short* __restrict__ wp,
                                               const float* __restrict__ hb0,
                                               const float* __restrict__ hb1,
                                               const float* __restrict__ hb2,
                                               unsigned short* __restrict__ pre,
                                               float* __restrict__ S) {
  __shared__ __align__(16) short lds[4 * 132 * 32];
  const int tid = threadIdx.x;
  const int r0 = blockIdx.y * 2, c0 = blockIdx.x * 128;
  const uint4* in4 = (const uint4*)(in + (size_t)blockIdx.z * PS1);
  unsigned short* prez = pre + (size_t)blockIdx.z * HWSZ * 16;
  float* Sz = S + blockIdx.z * 16;
  uint4* lds4 = (uint4*)lds;
  // stage 4 rows x 130 cols from chunk-major global into pixel-major swizzled LDS
  for (int i = tid; i < 4 * 4 * 130; i += 256) {
    int pcol = i % 130;
    int t = i / 130;
    int ch = t & 3;
    int prow = t >> 2;
    uint4 v = in4[(size_t)((r0 + prow) * 4 + ch) * PW + (c0 + pcol)];
    int pl = prow * 132 + pcol;
    lds4[pl * 4 + (ch ^ ((pl >> 1) & 3))] = v;
  }
  __syncthreads();

  const int lane = tid & 63, wid = tid >> 6;
  const int l15 = lane & 15, q = lane >> 4;
  const int rowsel = wid >> 1, half = wid & 1;

  f32x4 acc[4];
#pragma unroll
  for (int i = 0; i < 4; i++)
#pragma unroll
    for (int j = 0; j < 4; j++) acc[i][j] = 0.f;

#pragma unroll
  for (int dh = 0; dh < 3; dh++) {
    bf16x8 af[3];
#pragma unroll
    for (int dw = 0; dw < 3; dw++)
      af[dw] = *(const bf16x8*)(wp + ((dh * 3 + dw) * 16 + l15) * 32 + q * 8);
    const int lrow = (rowsel + dh) * 132;
#pragma unroll
    for (int dw = 0; dw < 3; dw++) {
#pragma unroll
      for (int nt = 0; nt < 4; nt++) {
        int pl = lrow + half * 64 + nt * 16 + l15 + dw;
        int blk = q ^ ((pl >> 1) & 3);
        bf16x8 b = *(const bf16x8*)(&lds[(pl * 4 + blk) * 8]);
        acc[nt] = __builtin_amdgcn_mfma_f32_16x16x32_bf16(af[dw], b, acc[nt], 0, 0, 0);
      }
    }
  }

  float bs[4];
#pragma unroll
  for (int r = 0; r < 4; r++) {
    int oc = q * 4 + r;
    bs[r] = oc < 4 ? hb0[oc] : (oc < 8 ? hb1[oc - 4] : (oc < 12 ? hb2[oc - 8] : 0.f));
  }
  float csum[4] = {0.f, 0.f, 0.f, 0.f};
  const int orow = r0 + rowsel;
#pragma unroll
  for (int nt = 0; nt < 4; nt++) {
    int pcol = c0 + half * 64 + nt * 16 + l15;
    int pix = orow * 512 + pcol;
    float v[4];
#pragma unroll
    for (int r = 0; r < 4; r++) {
      v[r] = acc[nt][r] + bs[r];
      csum[r] += v[r];
    }
    uint2 pk;
    pk.x = (unsigned)f2bf(v[0]) | ((unsigned)f2bf(v[1]) << 16);
    pk.y = (unsigned)f2bf(v[2]) | ((unsigned)f2bf(v[3]) << 16);
    *(uint2*)(prez + (size_t)pix * 16 + q * 4) = pk;
  }
#pragma unroll
  for (int d = 1; d < 16; d <<= 1)
#pragma unroll
    for (int r = 0; r < 4; r++) csum[r] += __shfl_xor(csum[r], d, 64);
  __shared__ float part[4][4][4];
  if (l15 == 0)
#pragma unroll
    for (int r = 0; r < 4; r++) part[wid][q][r] = csum[r];
  __syncthreads();
  if (tid < 12) {
    int oc = tid;
    float s = part[0][oc >> 2][oc & 3] + part[1][oc >> 2][oc & 3] +
              part[2][oc >> 2][oc & 3] + part[3][oc >> 2][oc & 3];
    atomicAdd(&Sz[oc], s);
  }
}

// ---- fused: gate + 3 box blurs + softmax(gate*pre) + weighted combine ----
#define BT 32
#define RAD 12
#define SRCT (BT + 2 * RAD)  // 56
__global__ __launch_bounds__(256) void k_blurcombine(const float* __restrict__ src,
                                                     const unsigned short* __restrict__ pre,
                                                     const float* __restrict__ S4,
                                                     const float* __restrict__ wa,
                                                     const float* __restrict__ wb,
                                                     float* __restrict__ dst) {
  __shared__ float tile[SRCT][SRCT];
  __shared__ float hs[3][SRCT][BT];
  __shared__ float g[4];
  const float* srcz = src + (size_t)blockIdx.z * HWSZ;
  const unsigned short* prez = pre + (size_t)blockIdx.z * HWSZ * 16;
  const float* S4z = S4 + blockIdx.z * 16;
  float* dstz = dst + (size_t)blockIdx.z * HWSZ;
  int h0 = blockIdx.y * BT - RAD, w0 = blockIdx.x * BT - RAD;
  if (threadIdx.x < 4) {
    int o = threadIdx.x;
    float m[4], ga[4];
#pragma unroll
    for (int c = 0; c < 4; c++) m[c] = S4z[c] * (1.0f / (float)HWSZ);
#pragma unroll
    for (int c = 0; c < 4; c++) {
      float s = 0.f;
#pragma unroll
      for (int j = 0; j < 4; j++) s = fmaf(wa[c * 4 + j], m[j], s);
      ga[c] = fmaxf(s, 0.f);
    }
    float s2 = 0.f;
#pragma unroll
    for (int c = 0; c < 4; c++) s2 = fmaf(wb[o * 4 + c], ga[c], s2);
    g[o] = 1.f / (1.f + expf(-s2));
  }
  for (int idx = threadIdx.x; idx < SRCT * SRCT; idx += 256) {
    int r = idx / SRCT, c = idx % SRCT;
    int hh = h0 + r, ww = w0 + c;
    float v = 0.f;
    if (hh >= 0 && hh < HH && ww >= 0 && ww < WW) v = srcz[hh * WW + ww];
    tile[r][c] = v;
  }
  __syncthreads();
  for (int idx = threadIdx.x; idx < SRCT * BT; idx += 256) {
    int r = idx / BT, j = idx % BT;
    int cc = j + RAD;
    float s5 = 0.f;
#pragma unroll
    for (int d = -2; d <= 2; d++) s5 += tile[r][cc + d];
    float s15 = s5;
#pragma unroll
    for (int d = 3; d <= 7; d++) s15 += tile[r][cc + d] + tile[r][cc - d];
    float s25 = s15;
#pragma unroll
    for (int d = 8; d <= 12; d++) s25 += tile[r][cc + d] + tile[r][cc - d];
    hs[0][r][j] = s5;
    hs[1][r][j] = s15;
    hs[2][r][j] = s25;
  }
  __syncthreads();
  for (int p = threadIdx.x; p < BT * BT; p += 256) {
    int i = p / BT, j = p % BT;
    int rr = i + RAD;
    float b1 = 0.f;
#pragma unroll
    for (int d = -2; d <= 2; d++) b1 += hs[0][rr + d][j];
    float b2 = 0.f;
#pragma unroll
    for (int d = -7; d <= 7; d++) b2 += hs[1][rr + d][j];
    float b3 = 0.f;
#pragma unroll
    for (int d = -12; d <= 12; d++) b3 += hs[2][rr + d][j];
    b1 *= (1.f / 25.f);
    b2 *= (1.f / 225.f);
    b3 *= (1.f / 625.f);
    float b0 = tile[rr][j + RAD];
    int y = blockIdx.y * BT + i, x = blockIdx.x * BT + j;
    int pix = y * WW + x;
    uint2 pk = *(const uint2*)(prez + (size_t)pix * 16);
    float v[4];
    v[0] = bf2f(pk.x & 0xffffu) * g[0];
    v[1] = bf2f(pk.x >> 16) * g[1];
    v[2] = bf2f(pk.y & 0xffffu) * g[2];
    v[3] = bf2f(pk.y >> 16) * g[3];
    float mx = fmaxf(fmaxf(v[0], v[1]), fmaxf(v[2], v[3]));
    float e0 = expf(v[0] - mx), e1 = expf(v[1] - mx), e2 = expf(v[2] - mx),
          e3 = expf(v[3] - mx);
    float inv = 1.f / (e0 + e1 + e2 + e3);
    dstz[pix] = (e0 * b0 + e1 * b1 + e2 * b2 + e3 * b3) * inv;
  }
}

extern "C" void kernel_launch(void* const* d_in, const int* in_sizes, int n_in,
                              void* d_out, int out_size, void* d_ws, size_t ws_size,
                              hipStream_t stream) {
  const float* x = (const float*)d_in[0];
  const float* w1 = (const float*)d_in[1];
  const float* b1 = (const float*)d_in[2];
  const float* a1 = (const float*)d_in[3];
  const float* w2 = (const float*)d_in[4];
  const float* b2 = (const float*)d_in[5];
  const float* a2 = (const float*)d_in[6];
  const float* w3 = (const float*)d_in[7];
  const float* b3 = (const float*)d_in[8];
  const float* a3 = (const float*)d_in[9];
  const float* hw[3] = {(const float*)d_in[10], (const float*)d_in[14], (const float*)d_in[18]};
  const float* hb[3] = {(const float*)d_in[11], (const float*)d_in[15], (const float*)d_in[19]};
  const float* caa[3] = {(const float*)d_in[12], (const float*)d_in[16], (const float*)d_in[20]};
  const float* cab[3] = {(const float*)d_in[13], (const float*)d_in[17], (const float*)d_in[21]};

  char* base = (char*)d_ws;
  size_t off = 0;
  auto alloc = [&](size_t bytes) {
    char* p = base + off;
    off = (off + bytes + 63) & ~(size_t)63;
    return p;
  };
  // group-of-4 batched buffers: ~244 MB total (ws is 256 MiB)
  unsigned short* t1 = (unsigned short*)alloc(4 * PS1 * 2);          // 67.9 MB
  unsigned short* t2 = (unsigned short*)alloc(4 * PS2 * 2);          // 135.8 MB
  unsigned short* pre = (unsigned short*)alloc(4 * (size_t)HWSZ * 16 * 2);  // 32 MB
  unsigned short* wp2 = (unsigned short*)alloc(9 * 64 * 32 * 2);
  unsigned short* wp3 = (unsigned short*)alloc(9 * 64 * 32 * 2);
  unsigned short* wph = (unsigned short*)alloc(9 * 16 * 32 * 2);
  float* out1 = (float*)alloc(4 * (size_t)HWSZ * 4);                 // 4 MB
  float* out2 = (float*)alloc(4 * (size_t)HWSZ * 4);                 // 4 MB
  float* S = (float*)alloc(8 * 16 * 4);

  dim3 blk(256);
  {
    int total = 9 * 64 * 32 + 9 * 32 * 64 + 9 * 16 * 32 + 4 * NZ1 + 4 * NZ2 + 128;
    k_prep<<<(total + 255) / 256, blk, 0, stream>>>(w2, w3, hw[0], hw[1], hw[2], wp2,
                                                    wp3, wph, t1, t2, S);
  }

  dim3 gc1(1024, 1, 4);
  dim3 gconv(8, 16, 4);     // 64-col strips x 32-row chunks x 4 images
  dim3 ghead(4, 256, 4);
  dim3 gbc(WW / BT, HH / BT, 4);
  for (int g = 0; g < 2; g++) {
    const float* xg = x + (size_t)g * 4 * HWSZ;
    float* Sg = S + g * 64;
    float* outg = (float*)d_out + (size_t)g * 4 * HWSZ;
    k_conv1<<<gc1, blk, 0, stream>>>(xg, w1, b1, a1, t1);
    k_convm<32, 64><<<gconv, blk, 0, stream>>>(t1, wp2, b2, a2, t2);
    k_convm<64, 32><<<gconv, blk, 0, stream>>>(t2, wp3, b3, a3, t1);
    k_headm<<<ghead, blk, 0, stream>>>(t1, wph, hb[0], hb[1], hb[2], pre, Sg);
    k_blurcombine<<<gbc, blk, 0, stream>>>(xg, pre + 0, Sg + 0, caa[0], cab[0], out1);
    k_blurcombine<<<gbc, blk, 0, stream>>>(out1, pre + 4, Sg + 4, caa[1], cab[1], out2);
    k_blurcombine<<<gbc, blk, 0, stream>>>(out2, pre + 8, Sg + 8, caa[2], cab[2], outg);
  }
}